// Round 7
// baseline (1615.006 us; speedup 1.0000x reference)
//
#include <hip/hip_runtime.h>

#define N_NODES 16384
#define E_EDGES 65536
#define HIDC 256
#define NM ((size_t)N_NODES * HIDC)       // 4194304
#define NSLOT 62
#define PLANEU ((size_t)NSLOT * 65536)    // ushorts per wprep plane
#define KMU ((size_t)N_NODES * 512)       // ushorts per km buffer

typedef __attribute__((ext_vector_type(8))) short short8;
typedef __attribute__((ext_vector_type(4))) float f32x4;

__device__ __forceinline__ float gelu_f(float x) {
  return 0.5f * x * (1.0f + tanhf(0.7978845608028654f * (x + 0.044715f * x * x * x)));
}
__device__ __forceinline__ unsigned short bf16rne(float x) {
  unsigned u = __float_as_uint(x);
  return (unsigned short)((u + 0x7FFFu + ((u >> 16) & 1u)) >> 16);
}
__device__ __forceinline__ void split2(float x, unsigned short& h, unsigned short& l) {
  h = bf16rne(x);
  float rem = x - __uint_as_float(((unsigned)h) << 16);
  l = bf16rne(rem);
}
__device__ __forceinline__ float bf2f(unsigned short v) {
  return __uint_as_float(((unsigned)v) << 16);
}
__device__ __forceinline__ int src_of(int r) { return (r == 0) ? 1 : (r == 2) ? 2 : 0; }
// wprep element offset within a slot: [nt(4)][ks(8)][kq(4)][n(64)][i(8)]
__device__ __forceinline__ size_t woff(int k, int n) {
  return (size_t)(((n >> 6) & 3) * 16384 + (k >> 5) * 2048 + (((k >> 3) & 3) * 512) + ((n & 63) * 8) + (k & 7));
}
// activation plane swizzle: MFMA-A-native. [row16][k8][row&15][k&7]
__device__ __forceinline__ size_t swz(int row, int k) {
  return ((size_t)(row >> 4) << 12) + ((size_t)(k >> 3) << 7) + ((row & 15) << 3) + (k & 7);
}

// ---------------- GEMM core: 64x64 tile, K=256, split-bf16 3-MFMA, LDS-free ----------------
// A planes are swz-layout; W slots are MFMA-native. All frag loads are coalesced b128.
__device__ __forceinline__ void gemm_core(const unsigned short* __restrict__ Ahi,
                                          const unsigned short* __restrict__ Alo,
                                          const unsigned short* __restrict__ Whi,
                                          const unsigned short* __restrict__ Wlo,
                                          int bm, int ntt, f32x4 (&acc)[2][2]) {
  const int tid = threadIdx.x;
  const int w = tid >> 6, l = tid & 63;
  const int mw = (w >> 1) * 32, nw = (w & 1) * 32;
  const int lk = l >> 4, ln = l & 15;
  const size_t abase = ((size_t)((bm + mw) >> 4) << 12) + ln * 8;           // + mf*4096 + (ks*4+lk)*128
  const size_t bbase = (size_t)ntt * 16384 + lk * 512 + (nw + ln) * 8;     // + ks*2048 + nf*128
  #pragma unroll 2
  for (int ks = 0; ks < 8; ks++) {
    short8 a_h[2], a_l[2], b_h[2], b_l[2];
    #pragma unroll
    for (int mf = 0; mf < 2; mf++) {
      size_t ao = abase + mf * 4096 + (size_t)(ks * 4 + lk) * 128;
      a_h[mf] = *(const short8*)(Ahi + ao);
      a_l[mf] = *(const short8*)(Alo + ao);
    }
    #pragma unroll
    for (int nf = 0; nf < 2; nf++) {
      size_t bo = bbase + ks * 2048 + nf * 128;
      b_h[nf] = *(const short8*)(Whi + bo);
      b_l[nf] = *(const short8*)(Wlo + bo);
    }
    #pragma unroll
    for (int mf = 0; mf < 2; mf++)
      #pragma unroll
      for (int nf = 0; nf < 2; nf++) {
        acc[mf][nf] = __builtin_amdgcn_mfma_f32_16x16x32_bf16(a_l[mf], b_h[nf], acc[mf][nf], 0, 0, 0);
        acc[mf][nf] = __builtin_amdgcn_mfma_f32_16x16x32_bf16(a_h[mf], b_l[nf], acc[mf][nf], 0, 0, 0);
        acc[mf][nf] = __builtin_amdgcn_mfma_f32_16x16x32_bf16(a_h[mf], b_h[nf], acc[mf][nf], 0, 0, 0);
      }
  }
}

// ---------------- batched per-layer GEMM: 3 Q jobs + 4 K|V double-wide jobs ----------------
// grid (256, 44): y<12 -> Q (t=y>>2, ntt=y&3); y>=12 -> KV (r=(y-12)>>3, nt8=(y-12)&7)
__global__ __launch_bounds__(256)
void gemm_layer(int l, const unsigned short* __restrict__ wprep,
                const unsigned short* __restrict__ hsP,
                const float* __restrict__ Qb, const float* __restrict__ fb,
                float* __restrict__ qb3, unsigned short* __restrict__ km) {
  const int y = blockIdx.y;
  const int bm = blockIdx.x * 64;
  const int tid = threadIdx.x;
  const int w = tid >> 6, lx = tid & 63;
  const int mw = (w >> 1) * 32, nw = (w & 1) * 32;
  const int lk = lx >> 4, ln = lx & 15;
  f32x4 acc[2][2];
  #pragma unroll
  for (int a = 0; a < 2; a++)
    #pragma unroll
    for (int b = 0; b < 2; b++) acc[a][b] = f32x4{0.f, 0.f, 0.f, 0.f};

  if (y < 12) {
    const int t = y >> 2, ntt = y & 3;
    const int slot = 3 + l * 3 + t;
    const unsigned short* Ah_ = hsP + (size_t)t * 2 * NM;
    gemm_core(Ah_, Ah_ + NM, wprep + (size_t)slot * 65536, wprep + PLANEU + (size_t)slot * 65536,
              bm, ntt, acc);
    const float* bias = Qb + (l * 3 + t) * 256;
    float* out = qb3 + (size_t)t * NM;
    #pragma unroll
    for (int nf = 0; nf < 2; nf++) {
      const int col = ntt * 64 + nw + nf * 16 + ln;
      const float bv = bias[col];
      #pragma unroll
      for (int mf = 0; mf < 2; mf++) {
        const int row = bm + mw + mf * 16 + lk * 4;
        #pragma unroll
        for (int r4 = 0; r4 < 4; r4++)
          out[(size_t)(row + r4) * HIDC + col] = acc[mf][nf][r4] + bv;
      }
    }
  } else {
    const int y2 = y - 12;
    const int r = y2 >> 3, nt8 = y2 & 7;
    const int lr = l * 4 + r;
    const int s = src_of(r);
    const int slot = 30 + lr * 2 + (nt8 >> 2);
    const int ntt = nt8 & 3;
    const unsigned short* Ah_ = hsP + (size_t)s * 2 * NM;
    gemm_core(Ah_, Ah_ + NM, wprep + (size_t)slot * 65536, wprep + PLANEU + (size_t)slot * 65536,
              bm, ntt, acc);
    unsigned short* kmr = km + (size_t)r * KMU;
    #pragma unroll
    for (int nf = 0; nf < 2; nf++) {
      const int c512 = nt8 * 64 + nw + nf * 16 + ln;
      const float bv = fb[lr * 512 + c512];
      #pragma unroll
      for (int mf = 0; mf < 2; mf++) {
        const int row = bm + mw + mf * 16 + lk * 4;
        #pragma unroll
        for (int r4 = 0; r4 < 4; r4++)
          kmr[(size_t)(row + r4) * 512 + c512] = bf16rne(acc[mf][nf][r4] + bv);
      }
    }
  }
}

// ---------------- batched 3-type GEMM (input proj / gelu / out proj) ----------------
// grid (256, 12): t=y>>2, ntt=y&3. OUTM: 0 = fp32 out (+t*NM), 1 = swz hi/lo planes (+t*2NM)
template<int OUTM>
__global__ __launch_bounds__(256)
void gemm3(const unsigned short* __restrict__ Abase, const unsigned short* __restrict__ wprep,
           int slot0, const float* __restrict__ bias0,
           float* __restrict__ outf, unsigned short* __restrict__ outP) {
  const int y = blockIdx.y;
  const int t = y >> 2, ntt = y & 3;
  const int bm = blockIdx.x * 64;
  const int tid = threadIdx.x;
  const int w = tid >> 6, lx = tid & 63;
  const int mw = (w >> 1) * 32, nw = (w & 1) * 32;
  const int lk = lx >> 4, ln = lx & 15;
  f32x4 acc[2][2];
  #pragma unroll
  for (int a = 0; a < 2; a++)
    #pragma unroll
    for (int b = 0; b < 2; b++) acc[a][b] = f32x4{0.f, 0.f, 0.f, 0.f};
  const unsigned short* Ah_ = Abase + (size_t)t * 2 * NM;
  const int slot = slot0 + t;
  gemm_core(Ah_, Ah_ + NM, wprep + (size_t)slot * 65536, wprep + PLANEU + (size_t)slot * 65536,
            bm, ntt, acc);
  const float* bias = bias0 + t * 256;
  #pragma unroll
  for (int nf = 0; nf < 2; nf++) {
    const int col = ntt * 64 + nw + nf * 16 + ln;
    const float bv = bias[col];
    #pragma unroll
    for (int mf = 0; mf < 2; mf++) {
      const int row = bm + mw + mf * 16 + lk * 4;
      #pragma unroll
      for (int r4 = 0; r4 < 4; r4++) {
        float val = acc[mf][nf][r4] + bv;
        if (OUTM == 0) {
          outf[(size_t)t * NM + (size_t)(row + r4) * HIDC + col] = val;
        } else {
          unsigned short h16, l16;
          split2(val, h16, l16);
          size_t o = swz(row + r4, col);
          outP[(size_t)t * 2 * NM + o] = h16;
          outP[(size_t)t * 2 * NM + NM + o] = l16;
        }
      }
    }
  }
}

// ---------------- x pre-split (into swz planes) ----------------
__global__ __launch_bounds__(256)
void split_x(const float* __restrict__ x0, const float* __restrict__ x1,
             const float* __restrict__ x2, unsigned short* __restrict__ out) {
  size_t gi = (size_t)blockIdx.x * 2048 + threadIdx.x * 8;
  int t = (int)(gi >> 22);
  size_t i = gi & (NM - 1);
  const float* x = t == 0 ? x0 : t == 1 ? x1 : x2;
  float4 v0 = *(const float4*)(x + i);
  float4 v1 = *(const float4*)(x + i + 4);
  float xs[8] = {v0.x, v0.y, v0.z, v0.w, v1.x, v1.y, v1.z, v1.w};
  short8 h8, l8;
  #pragma unroll
  for (int j = 0; j < 8; j++) {
    unsigned short h, lo;
    split2(xs[j], h, lo);
    h8[j] = (short)h; l8[j] = (short)lo;
  }
  int row = (int)(i >> 8), k = (int)(i & 255);
  size_t o = swz(row, k);
  unsigned short* hp = out + (size_t)t * 2 * NM;
  *(short8*)(hp + o) = h8;
  *(short8*)(hp + NM + o) = l8;
}

// ---------------- plain-weight prep (slots 0..29) ----------------
__global__ __launch_bounds__(256)
void prep_plain(const float* __restrict__ Win, const float* __restrict__ Qw,
                const float* __restrict__ Aw, const float* __restrict__ Wout,
                unsigned short* __restrict__ wh, unsigned short* __restrict__ wlo) {
  const int j = blockIdx.y;
  const float* src = j < 3  ? Win  + (size_t)j * 65536 :
                     j < 15 ? Qw   + (size_t)(j - 3) * 65536 :
                     j < 27 ? Aw   + (size_t)(j - 15) * 65536 :
                              Wout + (size_t)(j - 27) * 65536;
  const int c = blockIdx.x;
  const int nt = c >> 3, ks = c & 7;
  const int t = threadIdx.x;
  const int n = nt * 64 + (t & 63);
  const int kq = t >> 6;
  const int k = ks * 32 + kq * 8;
  short8 h8, l8;
  #pragma unroll
  for (int i = 0; i < 8; i++) {
    unsigned short h, lo;
    split2(src[(size_t)(k + i) * HIDC + n], h, lo);
    h8[i] = (short)h; l8[i] = (short)lo;
  }
  size_t off = (size_t)j * 65536 + nt * 16384 + ks * 2048 + kq * 512 + (size_t)(t & 63) * 8;
  *(short8*)&wh[off] = h8;
  *(short8*)&wlo[off] = l8;
}

// ---------------- fused K/V weight build (slots 30 + lr*2 + kv) ----------------
__global__ __launch_bounds__(256)
void fuse_kernel(const float* __restrict__ Kw, const float* __restrict__ Kb,
                 const float* __restrict__ Vw, const float* __restrict__ Vb,
                 const float* __restrict__ Arel, const float* __restrict__ Mrel,
                 unsigned short* __restrict__ wh, unsigned short* __restrict__ wlo,
                 float* __restrict__ fb) {
  const int h = blockIdx.x;
  const int lr = blockIdx.y;
  const int kv = blockIdx.z;
  const int l = lr >> 2, r = lr & 3;
  const int s = src_of(r);
  const float* Wsrc = (kv ? Vw : Kw) + (size_t)(l * 3 + s) * 65536;
  const float* bsrc = (kv ? Vb : Kb) + (size_t)(l * 3 + s) * 256;
  const float* A    = (kv ? Mrel : Arel) + (size_t)lr * 8192 + h * 1024;
  const int slot = 30 + lr * 2 + kv;
  float* fbp = fb + (size_t)lr * 512 + kv * 256;
  __shared__ float Am[32][32];
  const int tid = threadIdx.x;
  #pragma unroll
  for (int i = 0; i < 4; i++) { int p = tid + i * 256; Am[p >> 5][p & 31] = A[p]; }
  __syncthreads();
  float wv[32];
  #pragma unroll
  for (int d = 0; d < 32; d++) wv[d] = Wsrc[(size_t)tid * HIDC + h * 32 + d];
  const size_t sbase = (size_t)slot * 65536;
  #pragma unroll
  for (int e = 0; e < 32; e++) {
    float sacc = 0.0f;
    #pragma unroll
    for (int d = 0; d < 32; d++) sacc += wv[d] * Am[d][e];
    unsigned short hi, lo;
    split2(sacc, hi, lo);
    size_t o = sbase + woff(tid, h * 32 + e);
    wh[o] = hi; wlo[o] = lo;
  }
  if (tid < 32) {
    float sacc = 0.0f;
    #pragma unroll
    for (int d = 0; d < 32; d++) sacc += bsrc[h * 32 + d] * Am[d][tid];
    fbp[h * 32 + tid] = sacc;
  }
}

// ---------------- per-relation CSR build ----------------
__global__ __launch_bounds__(256)
void zero_cnt_kernel(int* __restrict__ cnt) {
  cnt[blockIdx.x * 256 + threadIdx.x] = 0;
}
__global__ __launch_bounds__(256)
void count_kernel(const int* __restrict__ e0, const int* __restrict__ e1,
                  const int* __restrict__ e2, const int* __restrict__ e3,
                  int* __restrict__ cnt) {
  int g = blockIdx.x * 256 + threadIdx.x;
  int r = g >> 16, e = g & 0xFFFF;
  const int* ei = (r == 0) ? e0 : (r == 1) ? e1 : (r == 2) ? e2 : e3;
  atomicAdd(&cnt[r * N_NODES + ei[E_EDGES + e]], 1);
}
__global__ __launch_bounds__(256)
void scan_kernel(const int* __restrict__ cnt, int* __restrict__ rp, int* __restrict__ cur) {
  const int r = blockIdx.x;
  const int* c = cnt + r * N_NODES;
  int* rpp = rp + r * (N_NODES + 1);
  int* u = cur + r * N_NODES;
  __shared__ int part[256];
  const int tid = threadIdx.x;
  const int base = tid * 64;
  int s = 0;
  for (int i = 0; i < 64; i++) s += c[base + i];
  part[tid] = s;
  __syncthreads();
  for (int off = 1; off < 256; off <<= 1) {
    int v = (tid >= off) ? part[tid - off] : 0;
    __syncthreads();
    part[tid] += v;
    __syncthreads();
  }
  int run = (tid == 0) ? 0 : part[tid - 1];
  for (int i = 0; i < 64; i++) {
    int idx = base + i;
    rpp[idx] = run;
    u[idx] = run;
    run += c[idx];
  }
  if (tid == 255) rpp[N_NODES] = run;
}
__global__ __launch_bounds__(256)
void fill_kernel(const int* __restrict__ e0, const int* __restrict__ e1,
                 const int* __restrict__ e2, const int* __restrict__ e3,
                 int* __restrict__ cur, int* __restrict__ srcl) {
  int g = blockIdx.x * 256 + threadIdx.x;
  int r = g >> 16, e = g & 0xFFFF;
  const int* ei = (r == 0) ? e0 : (r == 1) ? e1 : (r == 2) ? e2 : e3;
  int pos = atomicAdd(&cur[r * N_NODES + ei[E_EDGES + e]], 1);
  srcl[r * E_EDGES + pos] = ei[e];
}

// ---------------- batched attention: all 3 dst types, online softmax ----------------
// grid 3*4096 blocks; t = b>>12; node = (b&4095)*4 + wave. Epilogue: gelu + split (swz).
__global__ __launch_bounds__(256)
void attn_layer(int l, const float* __restrict__ qb3, const unsigned short* __restrict__ km,
                const float* __restrict__ Prel, const int* __restrict__ rp,
                const int* __restrict__ srcl, unsigned short* __restrict__ gp) {
  const int b = blockIdx.x;
  const int t = b >> 12;
  const int n = ((b & 4095) << 2) + (threadIdx.x >> 6);
  const int lane = threadIdx.x & 63;
  const int h = lane >> 3;
  const float scale = 0.17677669529663687f;   // 1/sqrt(32)
  const float* q = qb3 + (size_t)t * NM;
  float4 qv = *(const float4*)(q + (size_t)n * HIDC + lane * 4);
  float m = -INFINITY, den = 0.0f;
  float ax = 0.f, ay = 0.f, az = 0.f, aw = 0.f;

  auto run = [&](int r) {
    const unsigned short* kmr = km + (size_t)r * KMU;
    const float p = Prel[(l * 4 + r) * 8 + h] * scale;
    const int* rpp = rp + r * (N_NODES + 1);
    const int* sl = srcl + r * E_EDGES;
    const int beg = rpp[n], end = rpp[n + 1];
    for (int i = beg; i < end; i++) {
      int src = sl[i];
      const unsigned short* base = kmr + (size_t)src * 512 + lane * 4;
      uint2 uk = *(const uint2*)base;
      uint2 um = *(const uint2*)(base + 256);
      float k0 = __uint_as_float(uk.x << 16), k1 = __uint_as_float(uk.x & 0xFFFF0000u);
      float k2 = __uint_as_float(uk.y << 16), k3 = __uint_as_float(uk.y & 0xFFFF0000u);
      float dot = qv.x * k0 + qv.y * k1 + qv.z * k2 + qv.w * k3;
      dot += __shfl_xor(dot, 1);
      dot += __shfl_xor(dot, 2);
      dot += __shfl_xor(dot, 4);
      float s = dot * p;
      float mn = fmaxf(m, s);
      float c = expf(m - mn);
      float wgt = expf(s - mn);
      den = den * c + wgt;
      float m0 = __uint_as_float(um.x << 16), m1 = __uint_as_float(um.x & 0xFFFF0000u);
      float m2 = __uint_as_float(um.y << 16), m3 = __uint_as_float(um.y & 0xFFFF0000u);
      ax = ax * c + wgt * m0;
      ay = ay * c + wgt * m1;
      az = az * c + wgt * m2;
      aw = aw * c + wgt * m3;
      m = mn;
    }
  };
  if (t == 0) { run(0); run(3); }
  else if (t == 1) { run(2); }
  else { run(1); }

  float inv = 1.0f / fmaxf(den, 1e-16f);
  float vals[4] = {ax * inv, ay * inv, az * inv, aw * inv};
  unsigned short hh[4], ll[4];
  #pragma unroll
  for (int j = 0; j < 4; j++) split2(gelu_f(vals[j]), hh[j], ll[j]);
  unsigned hi01 = (unsigned)hh[0] | ((unsigned)hh[1] << 16);
  unsigned hi23 = (unsigned)hh[2] | ((unsigned)hh[3] << 16);
  unsigned lo01 = (unsigned)ll[0] | ((unsigned)ll[1] << 16);
  unsigned lo23 = (unsigned)ll[2] | ((unsigned)ll[3] << 16);
  unsigned short* oh = gp + (size_t)t * 2 * NM;
  // swz(n, lane*4): 4 consecutive k within one 8-block -> one uint2
  size_t o = ((size_t)(n >> 4) << 12) + ((size_t)(lane >> 1) << 7) + ((n & 15) << 3) + ((lane & 1) << 2);
  *(uint2*)(oh + o) = make_uint2(hi01, hi23);
  *(uint2*)(oh + NM + o) = make_uint2(lo01, lo23);
}

// ---------------- batched LN: skip-gate + residual + LayerNorm on swz hi/lo planes ----------------
__global__ __launch_bounds__(256)
void ln_layer(int l, const float* __restrict__ qb3, unsigned short* __restrict__ hsP,
              const float* __restrict__ skipA, const float* __restrict__ ln_g,
              const float* __restrict__ ln_b) {
  const int row = blockIdx.x;
  const int t = row >> 14;
  const int rr = row & 16383;
  const int tid = threadIdx.x;
  const int lt = l * 3 + t;
  float a = 1.0f / (1.0f + expf(-skipA[lt]));
  unsigned short* hH = hsP + (size_t)t * 2 * NM;
  unsigned short* hL = hH + NM;
  size_t off = swz(rr, tid);
  float hv = bf2f(hH[off]) + bf2f(hL[off]);
  float ov = qb3[(size_t)t * NM + (size_t)rr * HIDC + tid];
  float y = a * ov + (1.0f - a) * hv + hv;
  __shared__ float red[256];
  red[tid] = y;
  __syncthreads();
  #pragma unroll
  for (int o = 128; o > 0; o >>= 1) {
    if (tid < o) red[tid] += red[tid + o];
    __syncthreads();
  }
  float mu = red[0] * (1.0f / 256.0f);
  __syncthreads();
  float dv = y - mu;
  red[tid] = dv * dv;
  __syncthreads();
  #pragma unroll
  for (int o = 128; o > 0; o >>= 1) {
    if (tid < o) red[tid] += red[tid + o];
    __syncthreads();
  }
  float var = red[0] * (1.0f / 256.0f);
  float rs = 1.0f / sqrtf(var + 1e-5f);
  float out = dv * rs * ln_g[lt * 256 + tid] + ln_b[lt * 256 + tid];
  unsigned short h16, l16;
  split2(out, h16, l16);
  hH[off] = h16;
  hL[off] = l16;
}

extern "C" void kernel_launch(void* const* d_in, const int* in_sizes, int n_in,
                              void* d_out, int out_size, void* d_ws, size_t ws_size,
                              hipStream_t stream) {
  const float* x0 = (const float*)d_in[0];
  const float* x1 = (const float*)d_in[1];
  const float* x2 = (const float*)d_in[2];
  const int* ei[4] = {(const int*)d_in[3], (const int*)d_in[4], (const int*)d_in[5], (const int*)d_in[6]};
  const float* Win  = (const float*)d_in[7];
  const float* b_in = (const float*)d_in[8];
  const float* Kw   = (const float*)d_in[9];
  const float* Kb   = (const float*)d_in[10];
  const float* Qw   = (const float*)d_in[11];
  const float* Qb   = (const float*)d_in[12];
  const float* Vw   = (const float*)d_in[13];
  const float* Vb   = (const float*)d_in[14];
  const float* Arel = (const float*)d_in[15];
  const float* Mrel = (const float*)d_in[16];
  const float* Prel = (const float*)d_in[17];
  const float* Aw   = (const float*)d_in[18];
  const float* Ab   = (const float*)d_in[19];
  const float* skip = (const float*)d_in[20];
  const float* ln_g = (const float*)d_in[21];
  const float* ln_b = (const float*)d_in[22];
  const float* Wout = (const float*)d_in[23];
  const float* b_out= (const float*)d_in[24];

  // ---- workspace (~180 MB) ----
  float* f = (float*)d_ws;
  unsigned short* hsP = (unsigned short*)f;              // 3 x 2NM ushorts  [0,3NM)
  float* qb3 = f + 3 * NM;                               // 3 x NM fp32      [3NM,6NM)
  unsigned short* km = (unsigned short*)(f + 6 * NM);    // 4 x KMU ushorts  [6NM,10NM)
  unsigned short* wprep = (unsigned short*)(f + 10 * NM);// 2 x PLANEU ushorts
  float* fb = (float*)(wprep + 2 * PLANEU);              // 16 x 512
  int* ib = (int*)(fb + 8192);
  int* cnt  = ib;
  int* rp   = ib + 4 * N_NODES;
  int* cur  = rp + 4 * (N_NODES + 1);
  int* srcl = cur + 4 * N_NODES;
  unsigned short* gp = (unsigned short*)d_out;           // 3 x 2NM ushorts scratch

  // prep (weights, x planes, CSR) — rebuilt every call
  prep_plain<<<dim3(32, 30), 256, 0, stream>>>(Win, Qw, Aw, Wout, wprep, wprep + PLANEU);
  fuse_kernel<<<dim3(8, 16, 2), 256, 0, stream>>>(Kw, Kb, Vw, Vb, Arel, Mrel,
                                                  wprep, wprep + PLANEU, fb);
  split_x<<<3 * NM / 2048, 256, 0, stream>>>(x0, x1, x2, gp);
  zero_cnt_kernel<<<4 * N_NODES / 256, 256, 0, stream>>>(cnt);
  count_kernel<<<4 * E_EDGES / 256, 256, 0, stream>>>(ei[0], ei[1], ei[2], ei[3], cnt);
  scan_kernel<<<4, 256, 0, stream>>>(cnt, rp, cur);
  fill_kernel<<<4 * E_EDGES / 256, 256, 0, stream>>>(ei[0], ei[1], ei[2], ei[3], cur, srcl);

  // input projections: x planes -> hs planes
  gemm3<1><<<dim3(256, 12), 256, 0, stream>>>(gp, wprep, 0, b_in, nullptr, hsP);

  for (int l = 0; l < 4; l++) {
    gemm_layer<<<dim3(256, 44), 256, 0, stream>>>(l, wprep, hsP, Qb, fb, qb3, km);
    attn_layer<<<3 * 4096, 256, 0, stream>>>(l, qb3, km, Prel, rp, srcl, gp);
    gemm3<0><<<dim3(256, 12), 256, 0, stream>>>(gp, wprep, 15 + l * 3, Ab + l * 3 * 256,
                                                qb3, nullptr);
    ln_layer<<<3 * N_NODES, 256, 0, stream>>>(l, qb3, hsP, skip, ln_g, ln_b);
  }

  // output projections into d_out (fp32)
  gemm3<0><<<dim3(256, 12), 256, 0, stream>>>(hsP, wprep, 27, b_out, (float*)d_out, nullptr);
}

// Round 8
// 1210.205 us; speedup vs baseline: 1.3345x; 1.3345x over previous
//
#include <hip/hip_runtime.h>

#define N_NODES 16384
#define E_EDGES 65536
#define HIDC 256
#define NM ((size_t)N_NODES * HIDC)       // 4194304
#define NSLOT 62
#define PLANEU ((size_t)NSLOT * 65536)    // ushorts per wprep plane
#define KMU ((size_t)N_NODES * 512)       // ushorts per km buffer

typedef __attribute__((ext_vector_type(8))) short short8;
typedef __attribute__((ext_vector_type(4))) float f32x4;

__device__ __forceinline__ float gelu_f(float x) {
  return 0.5f * x * (1.0f + tanhf(0.7978845608028654f * (x + 0.044715f * x * x * x)));
}
__device__ __forceinline__ unsigned short bf16rne(float x) {
  unsigned u = __float_as_uint(x);
  return (unsigned short)((u + 0x7FFFu + ((u >> 16) & 1u)) >> 16);
}
__device__ __forceinline__ void split2(float x, unsigned short& h, unsigned short& l) {
  h = bf16rne(x);
  float rem = x - __uint_as_float(((unsigned)h) << 16);
  l = bf16rne(rem);
}
__device__ __forceinline__ float bf2f(unsigned short v) {
  return __uint_as_float(((unsigned)v) << 16);
}
__device__ __forceinline__ int src_of(int r) { return (r == 0) ? 1 : (r == 2) ? 2 : 0; }
// wprep element offset within a slot: [nt(4)][ks(8)][kq(4)][n(64)][i(8)]
__device__ __forceinline__ size_t woff(int k, int n) {
  return (size_t)(((n >> 6) & 3) * 16384 + (k >> 5) * 2048 + (((k >> 3) & 3) * 512) + ((n & 63) * 8) + (k & 7));
}
// activation plane swizzle: MFMA-A-native. [row16][k8][row&15][k&7]; 16-row group = 4096 contiguous
__device__ __forceinline__ size_t swz(int row, int k) {
  return ((size_t)(row >> 4) << 12) + ((size_t)(k >> 3) << 7) + ((row & 15) << 3) + (k & 7);
}

// ---------------- GEMM core: 64x64 tile, K=256, split-bf16 3-MFMA, LDS-free ----------------
__device__ __forceinline__ void gemm_core(const unsigned short* __restrict__ Ahi,
                                          const unsigned short* __restrict__ Alo,
                                          const unsigned short* __restrict__ Whi,
                                          const unsigned short* __restrict__ Wlo,
                                          int bm, int ntt, f32x4 (&acc)[2][2]) {
  const int tid = threadIdx.x;
  const int w = tid >> 6, l = tid & 63;
  const int mw = (w >> 1) * 32, nw = (w & 1) * 32;
  const int lk = l >> 4, ln = l & 15;
  const size_t abase = ((size_t)((bm + mw) >> 4) << 12) + ln * 8;           // + mf*4096 + (ks*4+lk)*128
  const size_t bbase = (size_t)ntt * 16384 + lk * 512 + (nw + ln) * 8;     // + ks*2048 + nf*128
  #pragma unroll 2
  for (int ks = 0; ks < 8; ks++) {
    short8 a_h[2], a_l[2], b_h[2], b_l[2];
    #pragma unroll
    for (int mf = 0; mf < 2; mf++) {
      size_t ao = abase + mf * 4096 + (size_t)(ks * 4 + lk) * 128;
      a_h[mf] = *(const short8*)(Ahi + ao);
      a_l[mf] = *(const short8*)(Alo + ao);
    }
    #pragma unroll
    for (int nf = 0; nf < 2; nf++) {
      size_t bo = bbase + ks * 2048 + nf * 128;
      b_h[nf] = *(const short8*)(Whi + bo);
      b_l[nf] = *(const short8*)(Wlo + bo);
    }
    #pragma unroll
    for (int mf = 0; mf < 2; mf++)
      #pragma unroll
      for (int nf = 0; nf < 2; nf++) {
        acc[mf][nf] = __builtin_amdgcn_mfma_f32_16x16x32_bf16(a_l[mf], b_h[nf], acc[mf][nf], 0, 0, 0);
        acc[mf][nf] = __builtin_amdgcn_mfma_f32_16x16x32_bf16(a_h[mf], b_l[nf], acc[mf][nf], 0, 0, 0);
        acc[mf][nf] = __builtin_amdgcn_mfma_f32_16x16x32_bf16(a_h[mf], b_h[nf], acc[mf][nf], 0, 0, 0);
      }
  }
}

// ---------------- batched per-layer GEMM: 3 Q jobs + 4 K|V double-wide jobs ----------------
__global__ __launch_bounds__(256)
void gemm_layer(int l, const unsigned short* __restrict__ wprep,
                const unsigned short* __restrict__ hsP,
                const float* __restrict__ Qb, const float* __restrict__ fb,
                float* __restrict__ qb3, unsigned short* __restrict__ km) {
  const int y = blockIdx.y;
  const int bm = blockIdx.x * 64;
  const int tid = threadIdx.x;
  const int w = tid >> 6, lx = tid & 63;
  const int mw = (w >> 1) * 32, nw = (w & 1) * 32;
  const int lk = lx >> 4, ln = lx & 15;
  f32x4 acc[2][2];
  #pragma unroll
  for (int a = 0; a < 2; a++)
    #pragma unroll
    for (int b = 0; b < 2; b++) acc[a][b] = f32x4{0.f, 0.f, 0.f, 0.f};

  if (y < 12) {
    const int t = y >> 2, ntt = y & 3;
    const int slot = 3 + l * 3 + t;
    const unsigned short* Ah_ = hsP + (size_t)t * 2 * NM;
    gemm_core(Ah_, Ah_ + NM, wprep + (size_t)slot * 65536, wprep + PLANEU + (size_t)slot * 65536,
              bm, ntt, acc);
    const float* bias = Qb + (l * 3 + t) * 256;
    float* out = qb3 + (size_t)t * NM;
    #pragma unroll
    for (int nf = 0; nf < 2; nf++) {
      const int col = ntt * 64 + nw + nf * 16 + ln;
      const float bv = bias[col];
      #pragma unroll
      for (int mf = 0; mf < 2; mf++) {
        const int row = bm + mw + mf * 16 + lk * 4;
        #pragma unroll
        for (int r4 = 0; r4 < 4; r4++)
          out[(size_t)(row + r4) * HIDC + col] = acc[mf][nf][r4] + bv;
      }
    }
  } else {
    const int y2 = y - 12;
    const int r = y2 >> 3, nt8 = y2 & 7;
    const int lr = l * 4 + r;
    const int s = src_of(r);
    const int slot = 30 + lr * 2 + (nt8 >> 2);
    const int ntt = nt8 & 3;
    const unsigned short* Ah_ = hsP + (size_t)s * 2 * NM;
    gemm_core(Ah_, Ah_ + NM, wprep + (size_t)slot * 65536, wprep + PLANEU + (size_t)slot * 65536,
              bm, ntt, acc);
    unsigned short* kmr = km + (size_t)r * KMU;
    #pragma unroll
    for (int nf = 0; nf < 2; nf++) {
      const int c512 = nt8 * 64 + nw + nf * 16 + ln;
      const float bv = fb[lr * 512 + c512];
      #pragma unroll
      for (int mf = 0; mf < 2; mf++) {
        const int row = bm + mw + mf * 16 + lk * 4;
        #pragma unroll
        for (int r4 = 0; r4 < 4; r4++)
          kmr[(size_t)(row + r4) * 512 + c512] = bf16rne(acc[mf][nf][r4] + bv);
      }
    }
  }
}

// ---------------- batched 3-type GEMM ----------------
// OUTM: 0 = fp32 row-major (+t*NM), 1 = swz hi/lo planes (+t*2NM), 2 = swz fp32 (+t*NM)
template<int OUTM>
__global__ __launch_bounds__(256)
void gemm3(const unsigned short* __restrict__ Abase, const unsigned short* __restrict__ wprep,
           int slot0, const float* __restrict__ bias0,
           float* __restrict__ outf, unsigned short* __restrict__ outP) {
  const int y = blockIdx.y;
  const int t = y >> 2, ntt = y & 3;
  const int bm = blockIdx.x * 64;
  const int tid = threadIdx.x;
  const int w = tid >> 6, lx = tid & 63;
  const int mw = (w >> 1) * 32, nw = (w & 1) * 32;
  const int lk = lx >> 4, ln = lx & 15;
  f32x4 acc[2][2];
  #pragma unroll
  for (int a = 0; a < 2; a++)
    #pragma unroll
    for (int b = 0; b < 2; b++) acc[a][b] = f32x4{0.f, 0.f, 0.f, 0.f};
  const unsigned short* Ah_ = Abase + (size_t)t * 2 * NM;
  const int slot = slot0 + t;
  gemm_core(Ah_, Ah_ + NM, wprep + (size_t)slot * 65536, wprep + PLANEU + (size_t)slot * 65536,
            bm, ntt, acc);
  const float* bias = bias0 + t * 256;
  #pragma unroll
  for (int nf = 0; nf < 2; nf++) {
    const int col = ntt * 64 + nw + nf * 16 + ln;
    const float bv = bias[col];
    #pragma unroll
    for (int mf = 0; mf < 2; mf++) {
      const int row = bm + mw + mf * 16 + lk * 4;
      #pragma unroll
      for (int r4 = 0; r4 < 4; r4++) {
        float val = acc[mf][nf][r4] + bv;
        if (OUTM == 0) {
          outf[(size_t)t * NM + (size_t)(row + r4) * HIDC + col] = val;
        } else if (OUTM == 1) {
          unsigned short h16, l16;
          split2(val, h16, l16);
          size_t o = swz(row + r4, col);
          outP[(size_t)t * 2 * NM + o] = h16;
          outP[(size_t)t * 2 * NM + NM + o] = l16;
        } else {
          outf[(size_t)t * NM + swz(row + r4, col)] = val;
        }
      }
    }
  }
}

// ---------------- x pre-split (into swz planes) ----------------
__global__ __launch_bounds__(256)
void split_x(const float* __restrict__ x0, const float* __restrict__ x1,
             const float* __restrict__ x2, unsigned short* __restrict__ out) {
  size_t gi = (size_t)blockIdx.x * 2048 + threadIdx.x * 8;
  int t = (int)(gi >> 22);
  size_t i = gi & (NM - 1);
  const float* x = t == 0 ? x0 : t == 1 ? x1 : x2;
  float4 v0 = *(const float4*)(x + i);
  float4 v1 = *(const float4*)(x + i + 4);
  float xs[8] = {v0.x, v0.y, v0.z, v0.w, v1.x, v1.y, v1.z, v1.w};
  short8 h8, l8;
  #pragma unroll
  for (int j = 0; j < 8; j++) {
    unsigned short h, lo;
    split2(xs[j], h, lo);
    h8[j] = (short)h; l8[j] = (short)lo;
  }
  int row = (int)(i >> 8), k = (int)(i & 255);
  size_t o = swz(row, k);
  unsigned short* hp = out + (size_t)t * 2 * NM;
  *(short8*)(hp + o) = h8;
  *(short8*)(hp + NM + o) = l8;
}

// ---------------- plain-weight prep (slots 0..29) ----------------
__global__ __launch_bounds__(256)
void prep_plain(const float* __restrict__ Win, const float* __restrict__ Qw,
                const float* __restrict__ Aw, const float* __restrict__ Wout,
                unsigned short* __restrict__ wh, unsigned short* __restrict__ wlo) {
  const int j = blockIdx.y;
  const float* src = j < 3  ? Win  + (size_t)j * 65536 :
                     j < 15 ? Qw   + (size_t)(j - 3) * 65536 :
                     j < 27 ? Aw   + (size_t)(j - 15) * 65536 :
                              Wout + (size_t)(j - 27) * 65536;
  const int c = blockIdx.x;
  const int nt = c >> 3, ks = c & 7;
  const int t = threadIdx.x;
  const int n = nt * 64 + (t & 63);
  const int kq = t >> 6;
  const int k = ks * 32 + kq * 8;
  short8 h8, l8;
  #pragma unroll
  for (int i = 0; i < 8; i++) {
    unsigned short h, lo;
    split2(src[(size_t)(k + i) * HIDC + n], h, lo);
    h8[i] = (short)h; l8[i] = (short)lo;
  }
  size_t off = (size_t)j * 65536 + nt * 16384 + ks * 2048 + kq * 512 + (size_t)(t & 63) * 8;
  *(short8*)&wh[off] = h8;
  *(short8*)&wlo[off] = l8;
}

// ---------------- fused K/V weight build (slots 30 + lr*2 + kv) ----------------
__global__ __launch_bounds__(256)
void fuse_kernel(const float* __restrict__ Kw, const float* __restrict__ Kb,
                 const float* __restrict__ Vw, const float* __restrict__ Vb,
                 const float* __restrict__ Arel, const float* __restrict__ Mrel,
                 unsigned short* __restrict__ wh, unsigned short* __restrict__ wlo,
                 float* __restrict__ fb) {
  const int h = blockIdx.x;
  const int lr = blockIdx.y;
  const int kv = blockIdx.z;
  const int l = lr >> 2, r = lr & 3;
  const int s = src_of(r);
  const float* Wsrc = (kv ? Vw : Kw) + (size_t)(l * 3 + s) * 65536;
  const float* bsrc = (kv ? Vb : Kb) + (size_t)(l * 3 + s) * 256;
  const float* A    = (kv ? Mrel : Arel) + (size_t)lr * 8192 + h * 1024;
  const int slot = 30 + lr * 2 + kv;
  float* fbp = fb + (size_t)lr * 512 + kv * 256;
  __shared__ float Am[32][32];
  const int tid = threadIdx.x;
  #pragma unroll
  for (int i = 0; i < 4; i++) { int p = tid + i * 256; Am[p >> 5][p & 31] = A[p]; }
  __syncthreads();
  float wv[32];
  #pragma unroll
  for (int d = 0; d < 32; d++) wv[d] = Wsrc[(size_t)tid * HIDC + h * 32 + d];
  const size_t sbase = (size_t)slot * 65536;
  #pragma unroll
  for (int e = 0; e < 32; e++) {
    float sacc = 0.0f;
    #pragma unroll
    for (int d = 0; d < 32; d++) sacc += wv[d] * Am[d][e];
    unsigned short hi, lo;
    split2(sacc, hi, lo);
    size_t o = sbase + woff(tid, h * 32 + e);
    wh[o] = hi; wlo[o] = lo;
  }
  if (tid < 32) {
    float sacc = 0.0f;
    #pragma unroll
    for (int d = 0; d < 32; d++) sacc += bsrc[h * 32 + d] * Am[d][tid];
    fbp[h * 32 + tid] = sacc;
  }
}

// ---------------- per-relation CSR build ----------------
__global__ __launch_bounds__(256)
void zero_cnt_kernel(int* __restrict__ cnt) {
  cnt[blockIdx.x * 256 + threadIdx.x] = 0;
}
__global__ __launch_bounds__(256)
void count_kernel(const int* __restrict__ e0, const int* __restrict__ e1,
                  const int* __restrict__ e2, const int* __restrict__ e3,
                  int* __restrict__ cnt) {
  int g = blockIdx.x * 256 + threadIdx.x;
  int r = g >> 16, e = g & 0xFFFF;
  const int* ei = (r == 0) ? e0 : (r == 1) ? e1 : (r == 2) ? e2 : e3;
  atomicAdd(&cnt[r * N_NODES + ei[E_EDGES + e]], 1);
}
__global__ __launch_bounds__(256)
void scan_kernel(const int* __restrict__ cnt, int* __restrict__ rp, int* __restrict__ cur) {
  const int r = blockIdx.x;
  const int* c = cnt + r * N_NODES;
  int* rpp = rp + r * (N_NODES + 1);
  int* u = cur + r * N_NODES;
  __shared__ int part[256];
  const int tid = threadIdx.x;
  const int base = tid * 64;
  int s = 0;
  for (int i = 0; i < 64; i++) s += c[base + i];
  part[tid] = s;
  __syncthreads();
  for (int off = 1; off < 256; off <<= 1) {
    int v = (tid >= off) ? part[tid - off] : 0;
    __syncthreads();
    part[tid] += v;
    __syncthreads();
  }
  int run = (tid == 0) ? 0 : part[tid - 1];
  for (int i = 0; i < 64; i++) {
    int idx = base + i;
    rpp[idx] = run;
    u[idx] = run;
    run += c[idx];
  }
  if (tid == 255) rpp[N_NODES] = run;
}
__global__ __launch_bounds__(256)
void fill_kernel(const int* __restrict__ e0, const int* __restrict__ e1,
                 const int* __restrict__ e2, const int* __restrict__ e3,
                 int* __restrict__ cur, int* __restrict__ srcl) {
  int g = blockIdx.x * 256 + threadIdx.x;
  int r = g >> 16, e = g & 0xFFFF;
  const int* ei = (r == 0) ? e0 : (r == 1) ? e1 : (r == 2) ? e2 : e3;
  int pos = atomicAdd(&cur[r * N_NODES + ei[E_EDGES + e]], 1);
  srcl[r * E_EDGES + pos] = ei[e];
}

// ---------------- batched attention: all 3 dst types, online softmax ----------------
__global__ __launch_bounds__(256)
void attn_layer(int l, const float* __restrict__ qb3, const unsigned short* __restrict__ km,
                const float* __restrict__ Prel, const int* __restrict__ rp,
                const int* __restrict__ srcl, unsigned short* __restrict__ gp) {
  const int b = blockIdx.x;
  const int t = b >> 12;
  const int n = ((b & 4095) << 2) + (threadIdx.x >> 6);
  const int lane = threadIdx.x & 63;
  const int h = lane >> 3;
  const float scale = 0.17677669529663687f;   // 1/sqrt(32)
  const float* q = qb3 + (size_t)t * NM;
  float4 qv = *(const float4*)(q + (size_t)n * HIDC + lane * 4);
  float m = -INFINITY, den = 0.0f;
  float ax = 0.f, ay = 0.f, az = 0.f, aw = 0.f;

  auto run = [&](int r) {
    const unsigned short* kmr = km + (size_t)r * KMU;
    const float p = Prel[(l * 4 + r) * 8 + h] * scale;
    const int* rpp = rp + r * (N_NODES + 1);
    const int* sl = srcl + r * E_EDGES;
    const int beg = rpp[n], end = rpp[n + 1];
    for (int i = beg; i < end; i++) {
      int src = sl[i];
      const unsigned short* base = kmr + (size_t)src * 512 + lane * 4;
      uint2 uk = *(const uint2*)base;
      uint2 um = *(const uint2*)(base + 256);
      float k0 = __uint_as_float(uk.x << 16), k1 = __uint_as_float(uk.x & 0xFFFF0000u);
      float k2 = __uint_as_float(uk.y << 16), k3 = __uint_as_float(uk.y & 0xFFFF0000u);
      float dot = qv.x * k0 + qv.y * k1 + qv.z * k2 + qv.w * k3;
      dot += __shfl_xor(dot, 1);
      dot += __shfl_xor(dot, 2);
      dot += __shfl_xor(dot, 4);
      float s = dot * p;
      float mn = fmaxf(m, s);
      float c = expf(m - mn);
      float wgt = expf(s - mn);
      den = den * c + wgt;
      float m0 = __uint_as_float(um.x << 16), m1 = __uint_as_float(um.x & 0xFFFF0000u);
      float m2 = __uint_as_float(um.y << 16), m3 = __uint_as_float(um.y & 0xFFFF0000u);
      ax = ax * c + wgt * m0;
      ay = ay * c + wgt * m1;
      az = az * c + wgt * m2;
      aw = aw * c + wgt * m3;
      m = mn;
    }
  };
  if (t == 0) { run(0); run(3); }
  else if (t == 1) { run(2); }
  else { run(1); }

  float inv = 1.0f / fmaxf(den, 1e-16f);
  float vals[4] = {ax * inv, ay * inv, az * inv, aw * inv};
  unsigned short hh[4], ll[4];
  #pragma unroll
  for (int j = 0; j < 4; j++) split2(gelu_f(vals[j]), hh[j], ll[j]);
  unsigned hi01 = (unsigned)hh[0] | ((unsigned)hh[1] << 16);
  unsigned hi23 = (unsigned)hh[2] | ((unsigned)hh[3] << 16);
  unsigned lo01 = (unsigned)ll[0] | ((unsigned)ll[1] << 16);
  unsigned lo23 = (unsigned)ll[2] | ((unsigned)ll[3] << 16);
  unsigned short* oh = gp + (size_t)t * 2 * NM;
  // swz(n, lane*4): one uint2 per lane; 4-row blocks fully cover 64B lines
  size_t o = ((size_t)(n >> 4) << 12) + ((size_t)(lane >> 1) << 7) + ((n & 15) << 3) + ((lane & 1) << 2);
  *(uint2*)(oh + o) = make_uint2(hi01, hi23);
  *(uint2*)(oh + NM + o) = make_uint2(lo01, lo23);
}

// ---------------- batched LN: one block per 16-row swz group, fully contiguous ----------------
// thread tid streams o = tid + j*256 (j=0..15); all its elements belong to row (tid>>3)&15,
// k_j = ((tid>>7) + 2j)*8 + (tid&7). Per-row reduce: 8-lane shfl + 2-wave LDS combine.
__global__ __launch_bounds__(256)
void ln_layer(int l, const float* __restrict__ qb3s, unsigned short* __restrict__ hsP,
              const float* __restrict__ skipA, const float* __restrict__ ln_g,
              const float* __restrict__ ln_b) {
  const int b = blockIdx.x;
  const int t = b >> 10;             // 3 types x 1024 groups
  const int grp = b & 1023;
  const int tid = threadIdx.x;
  const int lt = l * 3 + t;
  const float a = 1.0f / (1.0f + expf(-skipA[lt]));
  unsigned short* hH = hsP + (size_t)t * 2 * NM + (size_t)grp * 4096;
  unsigned short* hL = hH + NM;
  const float* ov = qb3s + (size_t)t * NM + (size_t)grp * 4096;
  float y[16];
  float s = 0.0f;
  #pragma unroll
  for (int j = 0; j < 16; j++) {
    int o = tid + j * 256;
    float hv = bf2f(hH[o]) + bf2f(hL[o]);
    float v = a * ov[o] + (1.0f - a) * hv + hv;
    y[j] = v;
    s += v;
  }
  s += __shfl_xor(s, 1); s += __shfl_xor(s, 2); s += __shfl_xor(s, 4);
  __shared__ float pa[4][8], pb[4][8];
  const int w = tid >> 6, lane = tid & 63;
  if ((lane & 7) == 0) pa[w][lane >> 3] = s;
  __syncthreads();
  const int r = (tid >> 3) & 15;
  float mu = (pa[r >> 3][r & 7] + pa[(r >> 3) + 2][r & 7]) * (1.0f / 256.0f);
  float sq = 0.0f;
  #pragma unroll
  for (int j = 0; j < 16; j++) { float d = y[j] - mu; sq += d * d; }
  sq += __shfl_xor(sq, 1); sq += __shfl_xor(sq, 2); sq += __shfl_xor(sq, 4);
  if ((lane & 7) == 0) pb[w][lane >> 3] = sq;
  __syncthreads();
  float var = (pb[r >> 3][r & 7] + pb[(r >> 3) + 2][r & 7]) * (1.0f / 256.0f);
  float rs = 1.0f / sqrtf(var + 1e-5f);
  const float* gv = ln_g + lt * 256;
  const float* bv = ln_b + lt * 256;
  #pragma unroll
  for (int j = 0; j < 16; j++) {
    int o = tid + j * 256;
    int k = ((tid >> 7) + 2 * j) * 8 + (tid & 7);
    float out = (y[j] - mu) * rs * gv[k] + bv[k];
    unsigned short h16, l16;
    split2(out, h16, l16);
    hH[o] = h16;
    hL[o] = l16;
  }
}

extern "C" void kernel_launch(void* const* d_in, const int* in_sizes, int n_in,
                              void* d_out, int out_size, void* d_ws, size_t ws_size,
                              hipStream_t stream) {
  const float* x0 = (const float*)d_in[0];
  const float* x1 = (const float*)d_in[1];
  const float* x2 = (const float*)d_in[2];
  const int* ei[4] = {(const int*)d_in[3], (const int*)d_in[4], (const int*)d_in[5], (const int*)d_in[6]};
  const float* Win  = (const float*)d_in[7];
  const float* b_in = (const float*)d_in[8];
  const float* Kw   = (const float*)d_in[9];
  const float* Kb   = (const float*)d_in[10];
  const float* Qw   = (const float*)d_in[11];
  const float* Qb   = (const float*)d_in[12];
  const float* Vw   = (const float*)d_in[13];
  const float* Vb   = (const float*)d_in[14];
  const float* Arel = (const float*)d_in[15];
  const float* Mrel = (const float*)d_in[16];
  const float* Prel = (const float*)d_in[17];
  const float* Aw   = (const float*)d_in[18];
  const float* Ab   = (const float*)d_in[19];
  const float* skip = (const float*)d_in[20];
  const float* ln_g = (const float*)d_in[21];
  const float* ln_b = (const float*)d_in[22];
  const float* Wout = (const float*)d_in[23];
  const float* b_out= (const float*)d_in[24];

  // ---- workspace (~180 MB) ----
  float* f = (float*)d_ws;
  unsigned short* hsP = (unsigned short*)f;              // 3 x 2NM ushorts  [0,3NM)
  float* qb3 = f + 3 * NM;                               // 3 x NM fp32      [3NM,6NM)
  unsigned short* km = (unsigned short*)(f + 6 * NM);    // 4 x KMU ushorts  [6NM,10NM)
  unsigned short* wprep = (unsigned short*)(f + 10 * NM);// 2 x PLANEU ushorts
  float* fb = (float*)(wprep + 2 * PLANEU);              // 16 x 512
  int* ib = (int*)(fb + 8192);
  int* cnt  = ib;
  int* rp   = ib + 4 * N_NODES;
  int* cur  = rp + 4 * (N_NODES + 1);
  int* srcl = cur + 4 * N_NODES;
  unsigned short* gp = (unsigned short*)d_out;           // 3 x 2NM ushorts scratch

  // prep (weights, x planes, CSR) — rebuilt every call
  prep_plain<<<dim3(32, 30), 256, 0, stream>>>(Win, Qw, Aw, Wout, wprep, wprep + PLANEU);
  fuse_kernel<<<dim3(8, 16, 2), 256, 0, stream>>>(Kw, Kb, Vw, Vb, Arel, Mrel,
                                                  wprep, wprep + PLANEU, fb);
  split_x<<<3 * NM / 2048, 256, 0, stream>>>(x0, x1, x2, gp);
  zero_cnt_kernel<<<4 * N_NODES / 256, 256, 0, stream>>>(cnt);
  count_kernel<<<4 * E_EDGES / 256, 256, 0, stream>>>(ei[0], ei[1], ei[2], ei[3], cnt);
  scan_kernel<<<4, 256, 0, stream>>>(cnt, rp, cur);
  fill_kernel<<<4 * E_EDGES / 256, 256, 0, stream>>>(ei[0], ei[1], ei[2], ei[3], cur, srcl);

  // input projections: x planes -> hs planes
  gemm3<1><<<dim3(256, 12), 256, 0, stream>>>(gp, wprep, 0, b_in, nullptr, hsP);

  for (int l = 0; l < 4; l++) {
    gemm_layer<<<dim3(256, 44), 256, 0, stream>>>(l, wprep, hsP, Qb, fb, qb3, km);
    attn_layer<<<3 * 4096, 256, 0, stream>>>(l, qb3, km, Prel, rp, srcl, gp);
    gemm3<2><<<dim3(256, 12), 256, 0, stream>>>(gp, wprep, 15 + l * 3, Ab + l * 3 * 256,
                                                qb3, nullptr);
    ln_layer<<<3 * 1024, 256, 0, stream>>>(l, qb3, hsP, skip, ln_g, ln_b);
  }

  // output projections into d_out (fp32)
  gemm3<0><<<dim3(256, 12), 256, 0, stream>>>(hsP, wprep, 27, b_out, (float*)d_out, nullptr);
}

// Round 9
// 1206.158 us; speedup vs baseline: 1.3390x; 1.0034x over previous
//
#include <hip/hip_runtime.h>

#define N_NODES 16384
#define E_EDGES 65536
#define HIDC 256
#define NM ((size_t)N_NODES * HIDC)       // 4194304
#define NSLOT 62
#define PLANEU ((size_t)NSLOT * 65536)    // ushorts per wprep plane
#define KMU ((size_t)N_NODES * 512)       // ushorts per km buffer

typedef __attribute__((ext_vector_type(8))) short short8;
typedef __attribute__((ext_vector_type(4))) float f32x4;

__device__ __forceinline__ float gelu_f(float x) {
  return 0.5f * x * (1.0f + tanhf(0.7978845608028654f * (x + 0.044715f * x * x * x)));
}
__device__ __forceinline__ unsigned short bf16rne(float x) {
  unsigned u = __float_as_uint(x);
  return (unsigned short)((u + 0x7FFFu + ((u >> 16) & 1u)) >> 16);
}
__device__ __forceinline__ void split2(float x, unsigned short& h, unsigned short& l) {
  h = bf16rne(x);
  float rem = x - __uint_as_float(((unsigned)h) << 16);
  l = bf16rne(rem);
}
__device__ __forceinline__ float bf2f(unsigned short v) {
  return __uint_as_float(((unsigned)v) << 16);
}
__device__ __forceinline__ int src_of(int r) { return (r == 0) ? 1 : (r == 2) ? 2 : 0; }
// wprep element offset within a slot: [nt(4)][ks(8)][kq(4)][n(64)][i(8)]
__device__ __forceinline__ size_t woff(int k, int n) {
  return (size_t)(((n >> 6) & 3) * 16384 + (k >> 5) * 2048 + (((k >> 3) & 3) * 512) + ((n & 63) * 8) + (k & 7));
}
// activation plane swizzle: MFMA-A-native. [row16][k8][row&15][k&7]; 16-row group = 4096 contiguous
__device__ __forceinline__ size_t swz(int row, int k) {
  return ((size_t)(row >> 4) << 12) + ((size_t)(k >> 3) << 7) + ((row & 15) << 3) + (k & 7);
}

// ---------------- GEMM core v2: block 128x64, 4 waves (2m x 2n), wave 64x32 ----------------
// Per wave per ks: 12 b128 loads -> 24 MFMA (2:1). LDS-free; A swz-layout, W MFMA-native.
__device__ __forceinline__ void gemm_core(const unsigned short* __restrict__ Ahi,
                                          const unsigned short* __restrict__ Alo,
                                          const unsigned short* __restrict__ Whi,
                                          const unsigned short* __restrict__ Wlo,
                                          int bm, int ntt, f32x4 (&acc)[4][2]) {
  const int tid = threadIdx.x;
  const int w = tid >> 6, l = tid & 63;
  const int wm = (w >> 1) * 64, wn = (w & 1) * 32;
  const int lk = l >> 4, ln = l & 15;
  const size_t abase = ((size_t)((bm + wm) >> 4) << 12) + ln * 8;        // + mf*4096 + (ks*4+lk)*128
  const size_t bbase = (size_t)ntt * 16384 + lk * 512 + (wn + ln) * 8;   // + ks*2048 + nf*128
  #pragma unroll 2
  for (int ks = 0; ks < 8; ks++) {
    short8 a_h[4], a_l[4], b_h[2], b_l[2];
    #pragma unroll
    for (int mf = 0; mf < 4; mf++) {
      size_t ao = abase + mf * 4096 + (size_t)(ks * 4 + lk) * 128;
      a_h[mf] = *(const short8*)(Ahi + ao);
      a_l[mf] = *(const short8*)(Alo + ao);
    }
    #pragma unroll
    for (int nf = 0; nf < 2; nf++) {
      size_t bo = bbase + ks * 2048 + nf * 128;
      b_h[nf] = *(const short8*)(Whi + bo);
      b_l[nf] = *(const short8*)(Wlo + bo);
    }
    #pragma unroll
    for (int mf = 0; mf < 4; mf++)
      #pragma unroll
      for (int nf = 0; nf < 2; nf++) {
        acc[mf][nf] = __builtin_amdgcn_mfma_f32_16x16x32_bf16(a_l[mf], b_h[nf], acc[mf][nf], 0, 0, 0);
        acc[mf][nf] = __builtin_amdgcn_mfma_f32_16x16x32_bf16(a_h[mf], b_l[nf], acc[mf][nf], 0, 0, 0);
        acc[mf][nf] = __builtin_amdgcn_mfma_f32_16x16x32_bf16(a_h[mf], b_h[nf], acc[mf][nf], 0, 0, 0);
      }
  }
}

// ---------------- batched per-layer GEMM: 3 Q jobs + 4 K|V double-wide jobs ----------------
// grid (128, 44): y<12 -> Q (t=y>>2, ntt=y&3); y>=12 -> KV (r=(y-12)>>3, nt8=(y-12)&7)
__global__ __launch_bounds__(256)
void gemm_layer(int l, const unsigned short* __restrict__ wprep,
                const unsigned short* __restrict__ hsP,
                const float* __restrict__ Qb, const float* __restrict__ fb,
                float* __restrict__ qb3, unsigned short* __restrict__ km) {
  const int y = blockIdx.y;
  const int bm = blockIdx.x * 128;
  const int tid = threadIdx.x;
  const int w = tid >> 6, lx = tid & 63;
  const int wm = (w >> 1) * 64, wn = (w & 1) * 32;
  const int lk = lx >> 4, ln = lx & 15;
  f32x4 acc[4][2];
  #pragma unroll
  for (int a = 0; a < 4; a++)
    #pragma unroll
    for (int b = 0; b < 2; b++) acc[a][b] = f32x4{0.f, 0.f, 0.f, 0.f};

  if (y < 12) {
    const int t = y >> 2, ntt = y & 3;
    const int slot = 3 + l * 3 + t;
    const unsigned short* Ah_ = hsP + (size_t)t * 2 * NM;
    gemm_core(Ah_, Ah_ + NM, wprep + (size_t)slot * 65536, wprep + PLANEU + (size_t)slot * 65536,
              bm, ntt, acc);
    const float* bias = Qb + (l * 3 + t) * 256;
    float* out = qb3 + (size_t)t * NM;
    #pragma unroll
    for (int nf = 0; nf < 2; nf++) {
      const int col = ntt * 64 + wn + nf * 16 + ln;
      const float bv = bias[col];
      #pragma unroll
      for (int mf = 0; mf < 4; mf++) {
        const int row = bm + wm + mf * 16 + lk * 4;
        #pragma unroll
        for (int r4 = 0; r4 < 4; r4++)
          out[(size_t)(row + r4) * HIDC + col] = acc[mf][nf][r4] + bv;
      }
    }
  } else {
    const int y2 = y - 12;
    const int r = y2 >> 3, nt8 = y2 & 7;
    const int lr = l * 4 + r;
    const int s = src_of(r);
    const int slot = 30 + lr * 2 + (nt8 >> 2);
    const int ntt = nt8 & 3;
    const unsigned short* Ah_ = hsP + (size_t)s * 2 * NM;
    gemm_core(Ah_, Ah_ + NM, wprep + (size_t)slot * 65536, wprep + PLANEU + (size_t)slot * 65536,
              bm, ntt, acc);
    unsigned short* kmr = km + (size_t)r * KMU;
    #pragma unroll
    for (int nf = 0; nf < 2; nf++) {
      const int c512 = nt8 * 64 + wn + nf * 16 + ln;
      const float bv = fb[lr * 512 + c512];
      #pragma unroll
      for (int mf = 0; mf < 4; mf++) {
        const int row = bm + wm + mf * 16 + lk * 4;
        #pragma unroll
        for (int r4 = 0; r4 < 4; r4++)
          kmr[(size_t)(row + r4) * 512 + c512] = bf16rne(acc[mf][nf][r4] + bv);
      }
    }
  }
}

// ---------------- batched 3-type GEMM ----------------
// grid (128, 12). OUTM: 0 = fp32 row-major (+t*NM), 1 = swz hi/lo planes (+t*2NM), 2 = swz fp32
template<int OUTM>
__global__ __launch_bounds__(256)
void gemm3(const unsigned short* __restrict__ Abase, const unsigned short* __restrict__ wprep,
           int slot0, const float* __restrict__ bias0,
           float* __restrict__ outf, unsigned short* __restrict__ outP) {
  const int y = blockIdx.y;
  const int t = y >> 2, ntt = y & 3;
  const int bm = blockIdx.x * 128;
  const int tid = threadIdx.x;
  const int w = tid >> 6, lx = tid & 63;
  const int wm = (w >> 1) * 64, wn = (w & 1) * 32;
  const int lk = lx >> 4, ln = lx & 15;
  f32x4 acc[4][2];
  #pragma unroll
  for (int a = 0; a < 4; a++)
    #pragma unroll
    for (int b = 0; b < 2; b++) acc[a][b] = f32x4{0.f, 0.f, 0.f, 0.f};
  const unsigned short* Ah_ = Abase + (size_t)t * 2 * NM;
  const int slot = slot0 + t;
  gemm_core(Ah_, Ah_ + NM, wprep + (size_t)slot * 65536, wprep + PLANEU + (size_t)slot * 65536,
            bm, ntt, acc);
  const float* bias = bias0 + t * 256;
  #pragma unroll
  for (int nf = 0; nf < 2; nf++) {
    const int col = ntt * 64 + wn + nf * 16 + ln;
    const float bv = bias[col];
    #pragma unroll
    for (int mf = 0; mf < 4; mf++) {
      const int row = bm + wm + mf * 16 + lk * 4;
      #pragma unroll
      for (int r4 = 0; r4 < 4; r4++) {
        float val = acc[mf][nf][r4] + bv;
        if (OUTM == 0) {
          outf[(size_t)t * NM + (size_t)(row + r4) * HIDC + col] = val;
        } else if (OUTM == 1) {
          unsigned short h16, l16;
          split2(val, h16, l16);
          size_t o = swz(row + r4, col);
          outP[(size_t)t * 2 * NM + o] = h16;
          outP[(size_t)t * 2 * NM + NM + o] = l16;
        } else {
          outf[(size_t)t * NM + swz(row + r4, col)] = val;
        }
      }
    }
  }
}

// ---------------- x pre-split (into swz planes) ----------------
__global__ __launch_bounds__(256)
void split_x(const float* __restrict__ x0, const float* __restrict__ x1,
             const float* __restrict__ x2, unsigned short* __restrict__ out) {
  size_t gi = (size_t)blockIdx.x * 2048 + threadIdx.x * 8;
  int t = (int)(gi >> 22);
  size_t i = gi & (NM - 1);
  const float* x = t == 0 ? x0 : t == 1 ? x1 : x2;
  float4 v0 = *(const float4*)(x + i);
  float4 v1 = *(const float4*)(x + i + 4);
  float xs[8] = {v0.x, v0.y, v0.z, v0.w, v1.x, v1.y, v1.z, v1.w};
  short8 h8, l8;
  #pragma unroll
  for (int j = 0; j < 8; j++) {
    unsigned short h, lo;
    split2(xs[j], h, lo);
    h8[j] = (short)h; l8[j] = (short)lo;
  }
  int row = (int)(i >> 8), k = (int)(i & 255);
  size_t o = swz(row, k);
  unsigned short* hp = out + (size_t)t * 2 * NM;
  *(short8*)(hp + o) = h8;
  *(short8*)(hp + NM + o) = l8;
}

// ---------------- plain-weight prep (slots 0..29) ----------------
__global__ __launch_bounds__(256)
void prep_plain(const float* __restrict__ Win, const float* __restrict__ Qw,
                const float* __restrict__ Aw, const float* __restrict__ Wout,
                unsigned short* __restrict__ wh, unsigned short* __restrict__ wlo) {
  const int j = blockIdx.y;
  const float* src = j < 3  ? Win  + (size_t)j * 65536 :
                     j < 15 ? Qw   + (size_t)(j - 3) * 65536 :
                     j < 27 ? Aw   + (size_t)(j - 15) * 65536 :
                              Wout + (size_t)(j - 27) * 65536;
  const int c = blockIdx.x;
  const int nt = c >> 3, ks = c & 7;
  const int t = threadIdx.x;
  const int n = nt * 64 + (t & 63);
  const int kq = t >> 6;
  const int k = ks * 32 + kq * 8;
  short8 h8, l8;
  #pragma unroll
  for (int i = 0; i < 8; i++) {
    unsigned short h, lo;
    split2(src[(size_t)(k + i) * HIDC + n], h, lo);
    h8[i] = (short)h; l8[i] = (short)lo;
  }
  size_t off = (size_t)j * 65536 + nt * 16384 + ks * 2048 + kq * 512 + (size_t)(t & 63) * 8;
  *(short8*)&wh[off] = h8;
  *(short8*)&wlo[off] = l8;
}

// ---------------- fused K/V weight build (slots 30 + lr*2 + kv) ----------------
__global__ __launch_bounds__(256)
void fuse_kernel(const float* __restrict__ Kw, const float* __restrict__ Kb,
                 const float* __restrict__ Vw, const float* __restrict__ Vb,
                 const float* __restrict__ Arel, const float* __restrict__ Mrel,
                 unsigned short* __restrict__ wh, unsigned short* __restrict__ wlo,
                 float* __restrict__ fb) {
  const int h = blockIdx.x;
  const int lr = blockIdx.y;
  const int kv = blockIdx.z;
  const int l = lr >> 2, r = lr & 3;
  const int s = src_of(r);
  const float* Wsrc = (kv ? Vw : Kw) + (size_t)(l * 3 + s) * 65536;
  const float* bsrc = (kv ? Vb : Kb) + (size_t)(l * 3 + s) * 256;
  const float* A    = (kv ? Mrel : Arel) + (size_t)lr * 8192 + h * 1024;
  const int slot = 30 + lr * 2 + kv;
  float* fbp = fb + (size_t)lr * 512 + kv * 256;
  __shared__ float Am[32][32];
  const int tid = threadIdx.x;
  #pragma unroll
  for (int i = 0; i < 4; i++) { int p = tid + i * 256; Am[p >> 5][p & 31] = A[p]; }
  __syncthreads();
  float wv[32];
  #pragma unroll
  for (int d = 0; d < 32; d++) wv[d] = Wsrc[(size_t)tid * HIDC + h * 32 + d];
  const size_t sbase = (size_t)slot * 65536;
  #pragma unroll
  for (int e = 0; e < 32; e++) {
    float sacc = 0.0f;
    #pragma unroll
    for (int d = 0; d < 32; d++) sacc += wv[d] * Am[d][e];
    unsigned short hi, lo;
    split2(sacc, hi, lo);
    size_t o = sbase + woff(tid, h * 32 + e);
    wh[o] = hi; wlo[o] = lo;
  }
  if (tid < 32) {
    float sacc = 0.0f;
    #pragma unroll
    for (int d = 0; d < 32; d++) sacc += bsrc[h * 32 + d] * Am[d][tid];
    fbp[h * 32 + tid] = sacc;
  }
}

// ---------------- per-relation CSR build ----------------
__global__ __launch_bounds__(256)
void zero_cnt_kernel(int* __restrict__ cnt) {
  cnt[blockIdx.x * 256 + threadIdx.x] = 0;
}
__global__ __launch_bounds__(256)
void count_kernel(const int* __restrict__ e0, const int* __restrict__ e1,
                  const int* __restrict__ e2, const int* __restrict__ e3,
                  int* __restrict__ cnt) {
  int g = blockIdx.x * 256 + threadIdx.x;
  int r = g >> 16, e = g & 0xFFFF;
  const int* ei = (r == 0) ? e0 : (r == 1) ? e1 : (r == 2) ? e2 : e3;
  atomicAdd(&cnt[r * N_NODES + ei[E_EDGES + e]], 1);
}
__global__ __launch_bounds__(256)
void scan_kernel(const int* __restrict__ cnt, int* __restrict__ rp, int* __restrict__ cur) {
  const int r = blockIdx.x;
  const int* c = cnt + r * N_NODES;
  int* rpp = rp + r * (N_NODES + 1);
  int* u = cur + r * N_NODES;
  __shared__ int part[256];
  const int tid = threadIdx.x;
  const int base = tid * 64;
  int s = 0;
  for (int i = 0; i < 64; i++) s += c[base + i];
  part[tid] = s;
  __syncthreads();
  for (int off = 1; off < 256; off <<= 1) {
    int v = (tid >= off) ? part[tid - off] : 0;
    __syncthreads();
    part[tid] += v;
    __syncthreads();
  }
  int run = (tid == 0) ? 0 : part[tid - 1];
  for (int i = 0; i < 64; i++) {
    int idx = base + i;
    rpp[idx] = run;
    u[idx] = run;
    run += c[idx];
  }
  if (tid == 255) rpp[N_NODES] = run;
}
__global__ __launch_bounds__(256)
void fill_kernel(const int* __restrict__ e0, const int* __restrict__ e1,
                 const int* __restrict__ e2, const int* __restrict__ e3,
                 int* __restrict__ cur, int* __restrict__ srcl) {
  int g = blockIdx.x * 256 + threadIdx.x;
  int r = g >> 16, e = g & 0xFFFF;
  const int* ei = (r == 0) ? e0 : (r == 1) ? e1 : (r == 2) ? e2 : e3;
  int pos = atomicAdd(&cur[r * N_NODES + ei[E_EDGES + e]], 1);
  srcl[r * E_EDGES + pos] = ei[e];
}

// ---------------- batched attention: all 3 dst types, online softmax ----------------
__global__ __launch_bounds__(256)
void attn_layer(int l, const float* __restrict__ qb3, const unsigned short* __restrict__ km,
                const float* __restrict__ Prel, const int* __restrict__ rp,
                const int* __restrict__ srcl, unsigned short* __restrict__ gp) {
  const int b = blockIdx.x;
  const int t = b >> 12;
  const int n = ((b & 4095) << 2) + (threadIdx.x >> 6);
  const int lane = threadIdx.x & 63;
  const int h = lane >> 3;
  const float scale = 0.17677669529663687f;   // 1/sqrt(32)
  const float* q = qb3 + (size_t)t * NM;
  float4 qv = *(const float4*)(q + (size_t)n * HIDC + lane * 4);
  float m = -INFINITY, den = 0.0f;
  float ax = 0.f, ay = 0.f, az = 0.f, aw = 0.f;

  auto run = [&](int r) {
    const unsigned short* kmr = km + (size_t)r * KMU;
    const float p = Prel[(l * 4 + r) * 8 + h] * scale;
    const int* rpp = rp + r * (N_NODES + 1);
    const int* sl = srcl + r * E_EDGES;
    const int beg = rpp[n], end = rpp[n + 1];
    for (int i = beg; i < end; i++) {
      int src = sl[i];
      const unsigned short* base = kmr + (size_t)src * 512 + lane * 4;
      uint2 uk = *(const uint2*)base;
      uint2 um = *(const uint2*)(base + 256);
      float k0 = __uint_as_float(uk.x << 16), k1 = __uint_as_float(uk.x & 0xFFFF0000u);
      float k2 = __uint_as_float(uk.y << 16), k3 = __uint_as_float(uk.y & 0xFFFF0000u);
      float dot = qv.x * k0 + qv.y * k1 + qv.z * k2 + qv.w * k3;
      dot += __shfl_xor(dot, 1);
      dot += __shfl_xor(dot, 2);
      dot += __shfl_xor(dot, 4);
      float s = dot * p;
      float mn = fmaxf(m, s);
      float c = expf(m - mn);
      float wgt = expf(s - mn);
      den = den * c + wgt;
      float m0 = __uint_as_float(um.x << 16), m1 = __uint_as_float(um.x & 0xFFFF0000u);
      float m2 = __uint_as_float(um.y << 16), m3 = __uint_as_float(um.y & 0xFFFF0000u);
      ax = ax * c + wgt * m0;
      ay = ay * c + wgt * m1;
      az = az * c + wgt * m2;
      aw = aw * c + wgt * m3;
      m = mn;
    }
  };
  if (t == 0) { run(0); run(3); }
  else if (t == 1) { run(2); }
  else { run(1); }

  float inv = 1.0f / fmaxf(den, 1e-16f);
  float vals[4] = {ax * inv, ay * inv, az * inv, aw * inv};
  unsigned short hh[4], ll[4];
  #pragma unroll
  for (int j = 0; j < 4; j++) split2(gelu_f(vals[j]), hh[j], ll[j]);
  unsigned hi01 = (unsigned)hh[0] | ((unsigned)hh[1] << 16);
  unsigned hi23 = (unsigned)hh[2] | ((unsigned)hh[3] << 16);
  unsigned lo01 = (unsigned)ll[0] | ((unsigned)ll[1] << 16);
  unsigned lo23 = (unsigned)ll[2] | ((unsigned)ll[3] << 16);
  unsigned short* oh = gp + (size_t)t * 2 * NM;
  size_t o = ((size_t)(n >> 4) << 12) + ((size_t)(lane >> 1) << 7) + ((n & 15) << 3) + ((lane & 1) << 2);
  *(uint2*)(oh + o) = make_uint2(hi01, hi23);
  *(uint2*)(oh + NM + o) = make_uint2(lo01, lo23);
}

// ---------------- batched LN: one block per 16-row swz group, fully contiguous ----------------
__global__ __launch_bounds__(256)
void ln_layer(int l, const float* __restrict__ qb3s, unsigned short* __restrict__ hsP,
              const float* __restrict__ skipA, const float* __restrict__ ln_g,
              const float* __restrict__ ln_b) {
  const int b = blockIdx.x;
  const int t = b >> 10;             // 3 types x 1024 groups
  const int grp = b & 1023;
  const int tid = threadIdx.x;
  const int lt = l * 3 + t;
  const float a = 1.0f / (1.0f + expf(-skipA[lt]));
  unsigned short* hH = hsP + (size_t)t * 2 * NM + (size_t)grp * 4096;
  unsigned short* hL = hH + NM;
  const float* ov = qb3s + (size_t)t * NM + (size_t)grp * 4096;
  float y[16];
  float s = 0.0f;
  #pragma unroll
  for (int j = 0; j < 16; j++) {
    int o = tid + j * 256;
    float hv = bf2f(hH[o]) + bf2f(hL[o]);
    float v = a * ov[o] + (1.0f - a) * hv + hv;
    y[j] = v;
    s += v;
  }
  s += __shfl_xor(s, 1); s += __shfl_xor(s, 2); s += __shfl_xor(s, 4);
  __shared__ float pa[4][8], pb[4][8];
  const int w = tid >> 6, lane = tid & 63;
  if ((lane & 7) == 0) pa[w][lane >> 3] = s;
  __syncthreads();
  const int r = (tid >> 3) & 15;
  float mu = (pa[r >> 3][r & 7] + pa[(r >> 3) + 2][r & 7]) * (1.0f / 256.0f);
  float sq = 0.0f;
  #pragma unroll
  for (int j = 0; j < 16; j++) { float d = y[j] - mu; sq += d * d; }
  sq += __shfl_xor(sq, 1); sq += __shfl_xor(sq, 2); sq += __shfl_xor(sq, 4);
  if ((lane & 7) == 0) pb[w][lane >> 3] = sq;
  __syncthreads();
  float var = (pb[r >> 3][r & 7] + pb[(r >> 3) + 2][r & 7]) * (1.0f / 256.0f);
  float rs = 1.0f / sqrtf(var + 1e-5f);
  const float* gv = ln_g + lt * 256;
  const float* bv = ln_b + lt * 256;
  #pragma unroll
  for (int j = 0; j < 16; j++) {
    int o = tid + j * 256;
    int k = ((tid >> 7) + 2 * j) * 8 + (tid & 7);
    float out = (y[j] - mu) * rs * gv[k] + bv[k];
    unsigned short h16, l16;
    split2(out, h16, l16);
    hH[o] = h16;
    hL[o] = l16;
  }
}

extern "C" void kernel_launch(void* const* d_in, const int* in_sizes, int n_in,
                              void* d_out, int out_size, void* d_ws, size_t ws_size,
                              hipStream_t stream) {
  const float* x0 = (const float*)d_in[0];
  const float* x1 = (const float*)d_in[1];
  const float* x2 = (const float*)d_in[2];
  const int* ei[4] = {(const int*)d_in[3], (const int*)d_in[4], (const int*)d_in[5], (const int*)d_in[6]};
  const float* Win  = (const float*)d_in[7];
  const float* b_in = (const float*)d_in[8];
  const float* Kw   = (const float*)d_in[9];
  const float* Kb   = (const float*)d_in[10];
  const float* Qw   = (const float*)d_in[11];
  const float* Qb   = (const float*)d_in[12];
  const float* Vw   = (const float*)d_in[13];
  const float* Vb   = (const float*)d_in[14];
  const float* Arel = (const float*)d_in[15];
  const float* Mrel = (const float*)d_in[16];
  const float* Prel = (const float*)d_in[17];
  const float* Aw   = (const float*)d_in[18];
  const float* Ab   = (const float*)d_in[19];
  const float* skip = (const float*)d_in[20];
  const float* ln_g = (const float*)d_in[21];
  const float* ln_b = (const float*)d_in[22];
  const float* Wout = (const float*)d_in[23];
  const float* b_out= (const float*)d_in[24];

  // ---- workspace (~180 MB) ----
  float* f = (float*)d_ws;
  unsigned short* hsP = (unsigned short*)f;              // 3 x 2NM ushorts  [0,3NM)
  float* qb3 = f + 3 * NM;                               // 3 x NM fp32      [3NM,6NM)
  unsigned short* km = (unsigned short*)(f + 6 * NM);    // 4 x KMU ushorts  [6NM,10NM)
  unsigned short* wprep = (unsigned short*)(f + 10 * NM);// 2 x PLANEU ushorts
  float* fb = (float*)(wprep + 2 * PLANEU);              // 16 x 512
  int* ib = (int*)(fb + 8192);
  int* cnt  = ib;
  int* rp   = ib + 4 * N_NODES;
  int* cur  = rp + 4 * (N_NODES + 1);
  int* srcl = cur + 4 * N_NODES;
  unsigned short* gp = (unsigned short*)d_out;           // 3 x 2NM ushorts scratch

  // prep (weights, x planes, CSR) — rebuilt every call
  prep_plain<<<dim3(32, 30), 256, 0, stream>>>(Win, Qw, Aw, Wout, wprep, wprep + PLANEU);
  fuse_kernel<<<dim3(8, 16, 2), 256, 0, stream>>>(Kw, Kb, Vw, Vb, Arel, Mrel,
                                                  wprep, wprep + PLANEU, fb);
  split_x<<<3 * NM / 2048, 256, 0, stream>>>(x0, x1, x2, gp);
  zero_cnt_kernel<<<4 * N_NODES / 256, 256, 0, stream>>>(cnt);
  count_kernel<<<4 * E_EDGES / 256, 256, 0, stream>>>(ei[0], ei[1], ei[2], ei[3], cnt);
  scan_kernel<<<4, 256, 0, stream>>>(cnt, rp, cur);
  fill_kernel<<<4 * E_EDGES / 256, 256, 0, stream>>>(ei[0], ei[1], ei[2], ei[3], cur, srcl);

  // input projections: x planes -> hs planes
  gemm3<1><<<dim3(128, 12), 256, 0, stream>>>(gp, wprep, 0, b_in, nullptr, hsP);

  for (int l = 0; l < 4; l++) {
    gemm_layer<<<dim3(128, 44), 256, 0, stream>>>(l, wprep, hsP, Qb, fb, qb3, km);
    attn_layer<<<3 * 4096, 256, 0, stream>>>(l, qb3, km, Prel, rp, srcl, gp);
    gemm3<2><<<dim3(128, 12), 256, 0, stream>>>(gp, wprep, 15 + l * 3, Ab + l * 3 * 256,
                                                qb3, nullptr);
    ln_layer<<<3 * 1024, 256, 0, stream>>>(l, qb3, hsP, skip, ln_g, ln_b);
  }

  // output projections into d_out (fp32)
  gemm3<0><<<dim3(128, 12), 256, 0, stream>>>(hsP, wprep, 27, b_out, (float*)d_out, nullptr);
}

// Round 11
// 1066.673 us; speedup vs baseline: 1.5141x; 1.1308x over previous
//
#include <hip/hip_runtime.h>

#define N_NODES 16384
#define E_EDGES 65536
#define HIDC 256
#define NM ((size_t)N_NODES * HIDC)       // 4194304
#define NSLOT 62
#define PLANEU ((size_t)NSLOT * 65536)    // ushorts per wprep plane
#define KMU ((size_t)N_NODES * 512)       // ushorts per km buffer

typedef __attribute__((ext_vector_type(8))) short short8;
typedef __attribute__((ext_vector_type(4))) float f32x4;

__device__ __forceinline__ float gelu_f(float x) {
  return 0.5f * x * (1.0f + tanhf(0.7978845608028654f * (x + 0.044715f * x * x * x)));
}
__device__ __forceinline__ unsigned short bf16rne(float x) {
  unsigned u = __float_as_uint(x);
  return (unsigned short)((u + 0x7FFFu + ((u >> 16) & 1u)) >> 16);
}
__device__ __forceinline__ void split2(float x, unsigned short& h, unsigned short& l) {
  h = bf16rne(x);
  float rem = x - __uint_as_float(((unsigned)h) << 16);
  l = bf16rne(rem);
}
__device__ __forceinline__ float bf2f(unsigned short v) {
  return __uint_as_float(((unsigned)v) << 16);
}
__device__ __forceinline__ int src_of(int r) { return (r == 0) ? 1 : (r == 2) ? 2 : 0; }
// wprep element offset within a slot: [nt(4)][ks(8)][kq(4)][n(64)][i(8)]
__device__ __forceinline__ size_t woff(int k, int n) {
  return (size_t)(((n >> 6) & 3) * 16384 + (k >> 5) * 2048 + (((k >> 3) & 3) * 512) + ((n & 63) * 8) + (k & 7));
}
// activation plane swizzle: MFMA-A-native. [row16][k8][row&15][k&7]; 16-row group = 4096 contiguous
__device__ __forceinline__ size_t swz(int row, int k) {
  return ((size_t)(row >> 4) << 12) + ((size_t)(k >> 3) << 7) + ((row & 15) << 3) + (k & 7);
}

// ======== A-stationary GEMM building blocks: block = 64-row stripe x 256 cols, 8 waves ========
// A stripe (hi+lo, 64 KB) staged once to LDS (contiguous copy thanks to swz layout).
// Per wave per ks: 8 ds_read_b128 (A) + 4 global b128 (B, L2-resident) -> 24 MFMA (6:1).
__device__ __forceinline__ void stage_A(const unsigned short* __restrict__ Ahi,
                                        const unsigned short* __restrict__ Alo,
                                        int stripe, short* AhS, short* AlS) {
  const int tid = threadIdx.x;
  const unsigned short* aH = Ahi + (size_t)stripe * 16384;
  const unsigned short* aL = Alo + (size_t)stripe * 16384;
  #pragma unroll
  for (int rnd = 0; rnd < 4; rnd++) {
    int idx = rnd * 4096 + tid * 8;
    *(short8*)&AhS[idx] = *(const short8*)(aH + idx);
    *(short8*)&AlS[idx] = *(const short8*)(aL + idx);
  }
  __syncthreads();
}

__device__ __forceinline__ void compute_tile(const short* AhS, const short* AlS,
                                             const unsigned short* __restrict__ Whi,
                                             const unsigned short* __restrict__ Wlo,
                                             size_t slotbase, f32x4 (&acc)[4][2]) {
  const int tid = threadIdx.x;
  const int w = tid >> 6, l = tid & 63;
  const int ntt = w >> 1, wn = (w & 1) * 32;
  const int lk = l >> 4, ln = l & 15;
  const size_t bbase = slotbase + ntt * 16384 + lk * 512 + (wn + ln) * 8;
  const int a0 = lk * 128 + ln * 8;
  #pragma unroll 2
  for (int ks = 0; ks < 8; ks++) {
    short8 b_h[2], b_l[2];
    #pragma unroll
    for (int nf = 0; nf < 2; nf++) {
      size_t bo = bbase + ks * 2048 + nf * 128;
      b_h[nf] = *(const short8*)(Whi + bo);
      b_l[nf] = *(const short8*)(Wlo + bo);
    }
    short8 a_h[4], a_l[4];
    #pragma unroll
    for (int mf = 0; mf < 4; mf++) {
      int ao = mf * 4096 + ks * 512 + a0;   // (ks*4+lk)*128 + ln*8
      a_h[mf] = *(const short8*)&AhS[ao];
      a_l[mf] = *(const short8*)&AlS[ao];
    }
    #pragma unroll
    for (int mf = 0; mf < 4; mf++)
      #pragma unroll
      for (int nf = 0; nf < 2; nf++) {
        acc[mf][nf] = __builtin_amdgcn_mfma_f32_16x16x32_bf16(a_l[mf], b_h[nf], acc[mf][nf], 0, 0, 0);
        acc[mf][nf] = __builtin_amdgcn_mfma_f32_16x16x32_bf16(a_h[mf], b_l[nf], acc[mf][nf], 0, 0, 0);
        acc[mf][nf] = __builtin_amdgcn_mfma_f32_16x16x32_bf16(a_h[mf], b_h[nf], acc[mf][nf], 0, 0, 0);
      }
  }
}

// ---------------- per-layer GEMM, A-stationary: grid (256 stripes, 11 groups) ----------------
// groups: y=0 Q(t0); y=1,2 r3 K|V halves; y=3,4 r1 K|V; y=5 Q(t1); y=6,7 r0; y=8 Q(t2); y=9,10 r2
__global__ __launch_bounds__(512)
void gemm_src(int l, const unsigned short* __restrict__ wprep,
              const unsigned short* __restrict__ hsP,
              const float* __restrict__ Qb, const float* __restrict__ fb,
              float* __restrict__ qb3, unsigned short* __restrict__ km) {
  __shared__ short AhS[16384], AlS[16384];
  const int y = blockIdx.y;
  const int stripe = blockIdx.x;
  int s, qt = -1, r = 0, half = 0;
  if (y == 0)      { s = 0; qt = 0; }
  else if (y < 5)  { s = 0; r = (y < 3) ? 3 : 1; half = (y == 2) | (y == 4); }
  else if (y == 5) { s = 1; qt = 1; }
  else if (y < 8)  { s = 1; r = 0; half = y - 6; }
  else if (y == 8) { s = 2; qt = 2; }
  else             { s = 2; r = 2; half = y - 9; }

  const unsigned short* Ah_ = hsP + (size_t)s * 2 * NM;
  stage_A(Ah_, Ah_ + NM, stripe, AhS, AlS);

  f32x4 acc[4][2];
  #pragma unroll
  for (int a = 0; a < 4; a++)
    #pragma unroll
    for (int b = 0; b < 2; b++) acc[a][b] = f32x4{0.f, 0.f, 0.f, 0.f};

  const int slot = (qt >= 0) ? (3 + l * 3 + qt) : (30 + (l * 4 + r) * 2 + half);
  compute_tile(AhS, AlS, wprep, wprep + PLANEU, (size_t)slot * 65536, acc);

  const int tid = threadIdx.x;
  const int w = tid >> 6, lx = tid & 63;
  const int ntt = w >> 1, wn = (w & 1) * 32;
  const int lk = lx >> 4, ln = lx & 15;

  if (qt >= 0) {
    const float* bias = Qb + (l * 3 + qt) * 256;
    float* out = qb3 + (size_t)qt * NM;
    #pragma unroll
    for (int nf = 0; nf < 2; nf++) {
      const int col = ntt * 64 + wn + nf * 16 + ln;
      const float bv = bias[col];
      #pragma unroll
      for (int mf = 0; mf < 4; mf++) {
        const int row = stripe * 64 + mf * 16 + lk * 4;
        #pragma unroll
        for (int r4 = 0; r4 < 4; r4++)
          out[(size_t)(row + r4) * HIDC + col] = acc[mf][nf][r4] + bv;
      }
    }
  } else {
    const int lr = l * 4 + r;
    const float* bias = fb + lr * 512 + half * 256;
    unsigned short* kmr = km + (size_t)r * KMU;
    #pragma unroll
    for (int nf = 0; nf < 2; nf++) {
      const int col = ntt * 64 + wn + nf * 16 + ln;
      const int c512 = half * 256 + col;
      const float bv = bias[col];
      #pragma unroll
      for (int mf = 0; mf < 4; mf++) {
        const int row = stripe * 64 + mf * 16 + lk * 4;
        #pragma unroll
        for (int r4 = 0; r4 < 4; r4++)
          kmr[(size_t)(row + r4) * 512 + c512] = bf16rne(acc[mf][nf][r4] + bv);
      }
    }
  }
}

// ---------------- 3-type GEMM, A-stationary: grid (256 stripes, 3 types) ----------------
// OUTM: 0 = fp32 row-major (+t*NM), 1 = swz hi/lo planes (+t*2NM), 2 = swz fp32 (+t*NM)
template<int OUTM>
__global__ __launch_bounds__(512)
void gemm3_s(const unsigned short* __restrict__ Abase, const unsigned short* __restrict__ wprep,
             int slot0, const float* __restrict__ bias0,
             float* __restrict__ outf, unsigned short* __restrict__ outP) {
  __shared__ short AhS[16384], AlS[16384];
  const int t = blockIdx.y;
  const int stripe = blockIdx.x;
  const unsigned short* Ah_ = Abase + (size_t)t * 2 * NM;
  stage_A(Ah_, Ah_ + NM, stripe, AhS, AlS);

  f32x4 acc[4][2];
  #pragma unroll
  for (int a = 0; a < 4; a++)
    #pragma unroll
    for (int b = 0; b < 2; b++) acc[a][b] = f32x4{0.f, 0.f, 0.f, 0.f};
  compute_tile(AhS, AlS, wprep, wprep + PLANEU, (size_t)(slot0 + t) * 65536, acc);

  const int tid = threadIdx.x;
  const int w = tid >> 6, lx = tid & 63;
  const int ntt = w >> 1, wn = (w & 1) * 32;
  const int lk = lx >> 4, ln = lx & 15;
  const float* bias = bias0 + t * 256;
  #pragma unroll
  for (int nf = 0; nf < 2; nf++) {
    const int col = ntt * 64 + wn + nf * 16 + ln;
    const float bv = bias[col];
    #pragma unroll
    for (int mf = 0; mf < 4; mf++) {
      const int row = stripe * 64 + mf * 16 + lk * 4;
      #pragma unroll
      for (int r4 = 0; r4 < 4; r4++) {
        float val = acc[mf][nf][r4] + bv;
        if (OUTM == 0) {
          outf[(size_t)t * NM + (size_t)(row + r4) * HIDC + col] = val;
        } else if (OUTM == 1) {
          unsigned short h16, l16;
          split2(val, h16, l16);
          size_t o = swz(row + r4, col);
          outP[(size_t)t * 2 * NM + o] = h16;
          outP[(size_t)t * 2 * NM + NM + o] = l16;
        } else {
          outf[(size_t)t * NM + swz(row + r4, col)] = val;
        }
      }
    }
  }
}

// ---------------- x pre-split (into swz planes) ----------------
__global__ __launch_bounds__(256)
void split_x(const float* __restrict__ x0, const float* __restrict__ x1,
             const float* __restrict__ x2, unsigned short* __restrict__ out) {
  size_t gi = (size_t)blockIdx.x * 2048 + threadIdx.x * 8;
  int t = (int)(gi >> 22);
  size_t i = gi & (NM - 1);
  const float* x = t == 0 ? x0 : t == 1 ? x1 : x2;
  float4 v0 = *(const float4*)(x + i);
  float4 v1 = *(const float4*)(x + i + 4);
  float xs[8] = {v0.x, v0.y, v0.z, v0.w, v1.x, v1.y, v1.z, v1.w};
  short8 h8, l8;
  #pragma unroll
  for (int j = 0; j < 8; j++) {
    unsigned short h, lo;
    split2(xs[j], h, lo);
    h8[j] = (short)h; l8[j] = (short)lo;
  }
  int row = (int)(i >> 8), k = (int)(i & 255);
  size_t o = swz(row, k);
  unsigned short* hp = out + (size_t)t * 2 * NM;
  *(short8*)(hp + o) = h8;
  *(short8*)(hp + NM + o) = l8;
}

// ---------------- plain-weight prep (slots 0..29) ----------------
__global__ __launch_bounds__(256)
void prep_plain(const float* __restrict__ Win, const float* __restrict__ Qw,
                const float* __restrict__ Aw, const float* __restrict__ Wout,
                unsigned short* __restrict__ wh, unsigned short* __restrict__ wlo) {
  const int j = blockIdx.y;
  const float* src = j < 3  ? Win  + (size_t)j * 65536 :
                     j < 15 ? Qw   + (size_t)(j - 3) * 65536 :
                     j < 27 ? Aw   + (size_t)(j - 15) * 65536 :
                              Wout + (size_t)(j - 27) * 65536;
  const int c = blockIdx.x;
  const int nt = c >> 3, ks = c & 7;
  const int t = threadIdx.x;
  const int n = nt * 64 + (t & 63);
  const int kq = t >> 6;
  const int k = ks * 32 + kq * 8;
  short8 h8, l8;
  #pragma unroll
  for (int i = 0; i < 8; i++) {
    unsigned short h, lo;
    split2(src[(size_t)(k + i) * HIDC + n], h, lo);
    h8[i] = (short)h; l8[i] = (short)lo;
  }
  size_t off = (size_t)j * 65536 + nt * 16384 + ks * 2048 + kq * 512 + (size_t)(t & 63) * 8;
  *(short8*)&wh[off] = h8;
  *(short8*)&wlo[off] = l8;
}

// ---------------- fused K/V weight build (slots 30 + lr*2 + kv) ----------------
__global__ __launch_bounds__(256)
void fuse_kernel(const float* __restrict__ Kw, const float* __restrict__ Kb,
                 const float* __restrict__ Vw, const float* __restrict__ Vb,
                 const float* __restrict__ Arel, const float* __restrict__ Mrel,
                 unsigned short* __restrict__ wh, unsigned short* __restrict__ wlo,
                 float* __restrict__ fb) {
  const int h = blockIdx.x;
  const int lr = blockIdx.y;
  const int kv = blockIdx.z;
  const int l = lr >> 2, r = lr & 3;
  const int s = src_of(r);
  const float* Wsrc = (kv ? Vw : Kw) + (size_t)(l * 3 + s) * 65536;
  const float* bsrc = (kv ? Vb : Kb) + (size_t)(l * 3 + s) * 256;
  const float* A    = (kv ? Mrel : Arel) + (size_t)lr * 8192 + h * 1024;
  const int slot = 30 + lr * 2 + kv;
  float* fbp = fb + (size_t)lr * 512 + kv * 256;
  __shared__ float Am[32][32];
  const int tid = threadIdx.x;
  #pragma unroll
  for (int i = 0; i < 4; i++) { int p = tid + i * 256; Am[p >> 5][p & 31] = A[p]; }
  __syncthreads();
  float wv[32];
  #pragma unroll
  for (int d = 0; d < 32; d++) wv[d] = Wsrc[(size_t)tid * HIDC + h * 32 + d];
  const size_t sbase = (size_t)slot * 65536;
  #pragma unroll
  for (int e = 0; e < 32; e++) {
    float sacc = 0.0f;
    #pragma unroll
    for (int d = 0; d < 32; d++) sacc += wv[d] * Am[d][e];
    unsigned short hi, lo;
    split2(sacc, hi, lo);
    size_t o = sbase + woff(tid, h * 32 + e);
    wh[o] = hi; wlo[o] = lo;
  }
  if (tid < 32) {
    float sacc = 0.0f;
    #pragma unroll
    for (int d = 0; d < 32; d++) sacc += bsrc[h * 32 + d] * Am[d][tid];
    fbp[h * 32 + tid] = sacc;
  }
}

// ---------------- per-relation CSR build ----------------
__global__ __launch_bounds__(256)
void zero_cnt_kernel(int* __restrict__ cnt) {
  cnt[blockIdx.x * 256 + threadIdx.x] = 0;
}
__global__ __launch_bounds__(256)
void count_kernel(const int* __restrict__ e0, const int* __restrict__ e1,
                  const int* __restrict__ e2, const int* __restrict__ e3,
                  int* __restrict__ cnt) {
  int g = blockIdx.x * 256 + threadIdx.x;
  int r = g >> 16, e = g & 0xFFFF;
  const int* ei = (r == 0) ? e0 : (r == 1) ? e1 : (r == 2) ? e2 : e3;
  atomicAdd(&cnt[r * N_NODES + ei[E_EDGES + e]], 1);
}
__global__ __launch_bounds__(256)
void scan_kernel(const int* __restrict__ cnt, int* __restrict__ rp, int* __restrict__ cur) {
  const int r = blockIdx.x;
  const int* c = cnt + r * N_NODES;
  int* rpp = rp + r * (N_NODES + 1);
  int* u = cur + r * N_NODES;
  __shared__ int part[256];
  const int tid = threadIdx.x;
  const int base = tid * 64;
  int s = 0;
  for (int i = 0; i < 64; i++) s += c[base + i];
  part[tid] = s;
  __syncthreads();
  for (int off = 1; off < 256; off <<= 1) {
    int v = (tid >= off) ? part[tid - off] : 0;
    __syncthreads();
    part[tid] += v;
    __syncthreads();
  }
  int run = (tid == 0) ? 0 : part[tid - 1];
  for (int i = 0; i < 64; i++) {
    int idx = base + i;
    rpp[idx] = run;
    u[idx] = run;
    run += c[idx];
  }
  if (tid == 255) rpp[N_NODES] = run;
}
__global__ __launch_bounds__(256)
void fill_kernel(const int* __restrict__ e0, const int* __restrict__ e1,
                 const int* __restrict__ e2, const int* __restrict__ e3,
                 int* __restrict__ cur, int* __restrict__ srcl) {
  int g = blockIdx.x * 256 + threadIdx.x;
  int r = g >> 16, e = g & 0xFFFF;
  const int* ei = (r == 0) ? e0 : (r == 1) ? e1 : (r == 2) ? e2 : e3;
  int pos = atomicAdd(&cur[r * N_NODES + ei[E_EDGES + e]], 1);
  srcl[r * E_EDGES + pos] = ei[e];
}

// ---------------- batched attention: all 3 dst types, online softmax ----------------
__global__ __launch_bounds__(256)
void attn_layer(int l, const float* __restrict__ qb3, const unsigned short* __restrict__ km,
                const float* __restrict__ Prel, const int* __restrict__ rp,
                const int* __restrict__ srcl, unsigned short* __restrict__ gp) {
  const int b = blockIdx.x;
  const int t = b >> 12;
  const int n = ((b & 4095) << 2) + (threadIdx.x >> 6);
  const int lane = threadIdx.x & 63;
  const int h = lane >> 3;
  const float scale = 0.17677669529663687f;   // 1/sqrt(32)
  const float* q = qb3 + (size_t)t * NM;
  float4 qv = *(const float4*)(q + (size_t)n * HIDC + lane * 4);
  float m = -INFINITY, den = 0.0f;
  float ax = 0.f, ay = 0.f, az = 0.f, aw = 0.f;

  auto run = [&](int r) {
    const unsigned short* kmr = km + (size_t)r * KMU;
    const float p = Prel[(l * 4 + r) * 8 + h] * scale;
    const int* rpp = rp + r * (N_NODES + 1);
    const int* sl = srcl + r * E_EDGES;
    const int beg = rpp[n], end = rpp[n + 1];
    for (int i = beg; i < end; i++) {
      int src = sl[i];
      const unsigned short* base = kmr + (size_t)src * 512 + lane * 4;
      uint2 uk = *(const uint2*)base;
      uint2 um = *(const uint2*)(base + 256);
      float k0 = __uint_as_float(uk.x << 16), k1 = __uint_as_float(uk.x & 0xFFFF0000u);
      float k2 = __uint_as_float(uk.y << 16), k3 = __uint_as_float(uk.y & 0xFFFF0000u);
      float dot = qv.x * k0 + qv.y * k1 + qv.z * k2 + qv.w * k3;
      dot += __shfl_xor(dot, 1);
      dot += __shfl_xor(dot, 2);
      dot += __shfl_xor(dot, 4);
      float s = dot * p;
      float mn = fmaxf(m, s);
      float c = expf(m - mn);
      float wgt = expf(s - mn);
      den = den * c + wgt;
      float m0 = __uint_as_float(um.x << 16), m1 = __uint_as_float(um.x & 0xFFFF0000u);
      float m2 = __uint_as_float(um.y << 16), m3 = __uint_as_float(um.y & 0xFFFF0000u);
      ax = ax * c + wgt * m0;
      ay = ay * c + wgt * m1;
      az = az * c + wgt * m2;
      aw = aw * c + wgt * m3;
      m = mn;
    }
  };
  if (t == 0) { run(0); run(3); }
  else if (t == 1) { run(2); }
  else { run(1); }

  float inv = 1.0f / fmaxf(den, 1e-16f);
  float vals[4] = {ax * inv, ay * inv, az * inv, aw * inv};
  unsigned short hh[4], ll[4];
  #pragma unroll
  for (int j = 0; j < 4; j++) split2(gelu_f(vals[j]), hh[j], ll[j]);
  unsigned hi01 = (unsigned)hh[0] | ((unsigned)hh[1] << 16);
  unsigned hi23 = (unsigned)hh[2] | ((unsigned)hh[3] << 16);
  unsigned lo01 = (unsigned)ll[0] | ((unsigned)ll[1] << 16);
  unsigned lo23 = (unsigned)ll[2] | ((unsigned)ll[3] << 16);
  unsigned short* oh = gp + (size_t)t * 2 * NM;
  size_t o = ((size_t)(n >> 4) << 12) + ((size_t)(lane >> 1) << 7) + ((n & 15) << 3) + ((lane & 1) << 2);
  *(uint2*)(oh + o) = make_uint2(hi01, hi23);
  *(uint2*)(oh + NM + o) = make_uint2(lo01, lo23);
}

// ---------------- batched LN: one block per 16-row swz group, fully contiguous ----------------
__global__ __launch_bounds__(256)
void ln_layer(int l, const float* __restrict__ qb3s, unsigned short* __restrict__ hsP,
              const float* __restrict__ skipA, const float* __restrict__ ln_g,
              const float* __restrict__ ln_b) {
  const int b = blockIdx.x;
  const int t = b >> 10;             // 3 types x 1024 groups
  const int grp = b & 1023;
  const int tid = threadIdx.x;
  const int lt = l * 3 + t;
  const float a = 1.0f / (1.0f + expf(-skipA[lt]));
  unsigned short* hH = hsP + (size_t)t * 2 * NM + (size_t)grp * 4096;
  unsigned short* hL = hH + NM;
  const float* ov = qb3s + (size_t)t * NM + (size_t)grp * 4096;
  float y[16];
  float s = 0.0f;
  #pragma unroll
  for (int j = 0; j < 16; j++) {
    int o = tid + j * 256;
    float hv = bf2f(hH[o]) + bf2f(hL[o]);
    float v = a * ov[o] + (1.0f - a) * hv + hv;
    y[j] = v;
    s += v;
  }
  s += __shfl_xor(s, 1); s += __shfl_xor(s, 2); s += __shfl_xor(s, 4);
  __shared__ float pa[4][8], pb[4][8];
  const int w = tid >> 6, lane = tid & 63;
  if ((lane & 7) == 0) pa[w][lane >> 3] = s;
  __syncthreads();
  const int r = (tid >> 3) & 15;
  float mu = (pa[r >> 3][r & 7] + pa[(r >> 3) + 2][r & 7]) * (1.0f / 256.0f);
  float sq = 0.0f;
  #pragma unroll
  for (int j = 0; j < 16; j++) { float d = y[j] - mu; sq += d * d; }
  sq += __shfl_xor(sq, 1); sq += __shfl_xor(sq, 2); sq += __shfl_xor(sq, 4);
  if ((lane & 7) == 0) pb[w][lane >> 3] = sq;
  __syncthreads();
  float var = (pb[r >> 3][r & 7] + pb[(r >> 3) + 2][r & 7]) * (1.0f / 256.0f);
  float rs = 1.0f / sqrtf(var + 1e-5f);
  const float* gv = ln_g + lt * 256;
  const float* bv = ln_b + lt * 256;
  #pragma unroll
  for (int j = 0; j < 16; j++) {
    int o = tid + j * 256;
    int k = ((tid >> 7) + 2 * j) * 8 + (tid & 7);
    float out = (y[j] - mu) * rs * gv[k] + bv[k];
    unsigned short h16, l16;
    split2(out, h16, l16);
    hH[o] = h16;
    hL[o] = l16;
  }
}

extern "C" void kernel_launch(void* const* d_in, const int* in_sizes, int n_in,
                              void* d_out, int out_size, void* d_ws, size_t ws_size,
                              hipStream_t stream) {
  const float* x0 = (const float*)d_in[0];
  const float* x1 = (const float*)d_in[1];
  const float* x2 = (const float*)d_in[2];
  const int* ei[4] = {(const int*)d_in[3], (const int*)d_in[4], (const int*)d_in[5], (const int*)d_in[6]};
  const float* Win  = (const float*)d_in[7];
  const float* b_in = (const float*)d_in[8];
  const float* Kw   = (const float*)d_in[9];
  const float* Kb   = (const float*)d_in[10];
  const float* Qw   = (const float*)d_in[11];
  const float* Qb   = (const float*)d_in[12];
  const float* Vw   = (const float*)d_in[13];
  const float* Vb   = (const float*)d_in[14];
  const float* Arel = (const float*)d_in[15];
  const float* Mrel = (const float*)d_in[16];
  const float* Prel = (const float*)d_in[17];
  const float* Aw   = (const float*)d_in[18];
  const float* Ab   = (const float*)d_in[19];
  const float* skip = (const float*)d_in[20];
  const float* ln_g = (const float*)d_in[21];
  const float* ln_b = (const float*)d_in[22];
  const float* Wout = (const float*)d_in[23];
  const float* b_out= (const float*)d_in[24];

  // ---- workspace (~180 MB) ----
  float* f = (float*)d_ws;
  unsigned short* hsP = (unsigned short*)f;              // 3 x 2NM ushorts  [0,3NM)
  float* qb3 = f + 3 * NM;                               // 3 x NM fp32      [3NM,6NM)
  unsigned short* km = (unsigned short*)(f + 6 * NM);    // 4 x KMU ushorts  [6NM,10NM)
  unsigned short* wprep = (unsigned short*)(f + 10 * NM);// 2 x PLANEU ushorts
  float* fb = (float*)(wprep + 2 * PLANEU);              // 16 x 512
  int* ib = (int*)(fb + 8192);
  int* cnt  = ib;
  int* rp   = ib + 4 * N_NODES;
  int* cur  = rp + 4 * (N_NODES + 1);
  int* srcl = cur + 4 * N_NODES;
  unsigned short* gp = (unsigned short*)d_out;           // 3 x 2NM ushorts scratch

  // prep (weights, x planes, CSR) — rebuilt every call
  prep_plain<<<dim3(32, 30), 256, 0, stream>>>(Win, Qw, Aw, Wout, wprep, wprep + PLANEU);
  fuse_kernel<<<dim3(8, 16, 2), 256, 0, stream>>>(Kw, Kb, Vw, Vb, Arel, Mrel,
                                                  wprep, wprep + PLANEU, fb);
  split_x<<<3 * NM / 2048, 256, 0, stream>>>(x0, x1, x2, gp);
  zero_cnt_kernel<<<4 * N_NODES / 256, 256, 0, stream>>>(cnt);
  count_kernel<<<4 * E_EDGES / 256, 256, 0, stream>>>(ei[0], ei[1], ei[2], ei[3], cnt);
  scan_kernel<<<4, 256, 0, stream>>>(cnt, rp, cur);
  fill_kernel<<<4 * E_EDGES / 256, 256, 0, stream>>>(ei[0], ei[1], ei[2], ei[3], cur, srcl);

  // input projections: x planes -> hs planes
  gemm3_s<1><<<dim3(256, 3), 512, 0, stream>>>(gp, wprep, 0, b_in, nullptr, hsP);

  for (int l = 0; l < 4; l++) {
    gemm_src<<<dim3(256, 11), 512, 0, stream>>>(l, wprep, hsP, Qb, fb, qb3, km);
    attn_layer<<<3 * 4096, 256, 0, stream>>>(l, qb3, km, Prel, rp, srcl, gp);
    gemm3_s<2><<<dim3(256, 3), 512, 0, stream>>>(gp, wprep, 15 + l * 3, Ab + l * 3 * 256,
                                                 qb3, nullptr);
    ln_layer<<<3 * 1024, 256, 0, stream>>>(l, qb3, hsP, skip, ln_g, ln_b);
  }

  // output projections into d_out (fp32)
  gemm3_s<0><<<dim3(256, 3), 512, 0, stream>>>(hsP, wprep, 27, b_out, (float*)d_out, nullptr);
}